// Round 4
// baseline (392.429 us; speedup 1.0000x reference)
//
#include <hip/hip_runtime.h>

// ---------------------------------------------------------------------------
// GCN encoder (4 conv layers, shared CSR graph) + 3-layer MLP decoder.
// Round 20: restore gather concurrency inside the fused agg+GEMM structure.
// R19 post-mortem: fused kernels were latency-bound (MfmaUtil 4%, VALU 26%,
// HBM 12%, occ 21.7%) — 8-deep serial node loop per quarter-wave + only 782
// blocks killed TLP vs the old 6250-block agg. Fix: 512-thread blocks
// (8 waves, 16-row GEMM tile per wave), serial depth 8->4, rowptr hoisted,
// next-iteration col loads issued under current gather latency.
// ---------------------------------------------------------------------------

typedef __attribute__((ext_vector_type(8))) short short8;
typedef __attribute__((ext_vector_type(4))) float floatx4;
typedef __attribute__((ext_vector_type(2))) float floatx2;

#define BIN_CH 8192          // edges per bin block
#define NBMAX 512            // max buckets supported
#define BKT 256              // nodes per bucket
#define HS_STRIDE 68         // LDS row stride in ushorts (136 B)

__device__ __forceinline__ unsigned short f2bf(float f) {
    unsigned int u = __float_as_uint(f);
    u += 0x7fffu + ((u >> 16) & 1u);          // round-to-nearest-even
    return (unsigned short)(u >> 16);
}
__device__ __forceinline__ unsigned int pk_bf(float a, float b) {
    return (unsigned int)f2bf(a) | ((unsigned int)f2bf(b) << 16);
}
__device__ __forceinline__ unsigned char f2fp8(float f) {
    return (unsigned char)(__builtin_amdgcn_cvt_pk_fp8_f32(f, f, 0, false) & 0xFF);
}
__device__ __forceinline__ short8 ld_frag(const unsigned short* p) {
    uint2 a = *(const uint2*)p;
    uint2 b = *(const uint2*)(p + 4);
    int4 v = make_int4((int)a.x, (int)a.y, (int)b.x, (int)b.y);
    return __builtin_bit_cast(short8, v);
}

// ---- weight pre-pack + buffer init (runs first) ---------------------------

__global__ void pack_kernel(const float* __restrict__ W0, const float* __restrict__ W1,
                            const float* __restrict__ W2, const float* __restrict__ W3,
                            unsigned short* __restrict__ P0, unsigned short* __restrict__ P1,
                            unsigned short* __restrict__ P2, unsigned short* __restrict__ P3,
                            int* __restrict__ gfill, unsigned char* __restrict__ t8zrowA,
                            unsigned char* __restrict__ t8zrowB, int NB) {
    if (blockIdx.x == 0) {                       // fold the memsets
        for (int i = threadIdx.x; i < NB; i += 256) gfill[i] = 0;
        if (threadIdx.x < 32) {
            ((unsigned int*)t8zrowA)[threadIdx.x] = 0;
            ((unsigned int*)t8zrowB)[threadIdx.x] = 0;
        }
    }
    int which = blockIdx.x >> 3;
    const float* W = which == 0 ? W0 : which == 1 ? W1 : which == 2 ? W2 : W3;
    unsigned short* P = which == 0 ? P0 : which == 1 ? P1 : which == 2 ? P2 : P3;
    int f = (blockIdx.x & 7) * 256 + threadIdx.x;
    int lane = f & 63, nt = (f >> 6) & 7, kc = f >> 9;
    int kbase = kc * 32 + (lane >> 4) * 8;
    int ncol = nt * 16 + (lane & 15);
    short8 frag;
    #pragma unroll
    for (int j = 0; j < 8; ++j)
        frag[j] = (short)f2bf(W[(size_t)(kbase + j) * 128 + ncol]);
    *((short8*)(P + (size_t)f * 8)) = frag;
}

// ---- graph build ----------------------------------------------------------
// entry = (d & 255) << 17 | src   (src < 2^17)

__global__ __launch_bounds__(512) void bin_kernel(
        const int* __restrict__ src, const int* __restrict__ dst,
        int* __restrict__ gfill, unsigned int* __restrict__ binbuf,
        int NB, int C, int E) {
    __shared__ int h4[4][NBMAX];     // per-group counts -> cursors
    __shared__ int start[NBMAX];
    __shared__ int tot[NBMAX];
    __shared__ int dstoff[NBMAX];
    int tid = threadIdx.x;
    int grp = tid >> 7;
    int e0 = blockIdx.x * BIN_CH;
    for (int i = tid; i < 4 * NBMAX; i += 512) ((int*)h4)[i] = 0;
    __syncthreads();
    for (int i = tid; i < BIN_CH; i += 512) {
        int e = e0 + i;
        if (e < E) atomicAdd(&h4[grp][dst[e] >> 8], 1);
    }
    __syncthreads();
    if (tid < 64) {        // wave 0: totals, exclusive scan, per-group bases
        int carry = 0;
        for (int base = 0; base < NB; base += 64) {
            int idx = base + tid;
            int c0 = 0, c1 = 0, c2 = 0, c3 = 0, v = 0;
            if (idx < NB) {
                c0 = h4[0][idx]; c1 = h4[1][idx];
                c2 = h4[2][idx]; c3 = h4[3][idx];
                v = c0 + c1 + c2 + c3;
            }
            int s = v;
            #pragma unroll
            for (int off = 1; off < 64; off <<= 1) {
                int u = __shfl_up(s, off);
                if (tid >= off) s += u;
            }
            if (idx < NB) {
                int ex = carry + s - v;
                start[idx] = ex;
                tot[idx] = v;
                h4[0][idx] = ex;
                h4[1][idx] = ex + c0;
                h4[2][idx] = ex + c0 + c1;
                h4[3][idx] = ex + c0 + c1 + c2;
            }
            carry += __shfl(s, 63);
        }
    }
    __syncthreads();
    for (int i = tid; i < NB; i += 512) {   // reserve global runs
        int cnt = tot[i];
        int g = cnt ? atomicAdd(&gfill[i], cnt) : 0;
        dstoff[i] = g - start[i];
    }
    __syncthreads();
    for (int i = tid; i < BIN_CH; i += 512) {
        int e = e0 + i;
        if (e >= E) continue;
        int d = dst[e];
        int b = d >> 8;
        int slot = atomicAdd(&h4[grp][b], 1);         // block-local rank
        int gidx = b * C + dstoff[b] + slot;
        if (gidx < (b + 1) * C)
            binbuf[gidx] = (unsigned int)src[e] | ((unsigned int)(d & 255) << 17);
    }
}

// one block per bucket: split hist(4x256) -> scan -> rowptr/dinv -> place.
// Bucket base computed in-kernel (wave 1 sums gfill[0..b)).
__global__ __launch_bounds__(256) void build_kernel(
        const unsigned int* __restrict__ binbuf, const int* __restrict__ gfill,
        int* __restrict__ rowptr, float* __restrict__ dinv, int* __restrict__ col,
        int NB, int C, int N, int E) {
    __shared__ int h4[4][BKT];       // per-group counts -> cursors
    __shared__ int hs[BKT];          // exclusive scan of totals
    __shared__ int tot[BKT];
    __shared__ int bbase_s;
    int b = blockIdx.x, tid = threadIdx.x;
    int grp = tid >> 6;
    int cnt = gfill[b];
    const unsigned int* p = binbuf + (size_t)b * C;
    for (int i = tid; i < 4 * BKT; i += 256) ((int*)h4)[i] = 0;
    __syncthreads();
    if (tid >= 64 && tid < 128) {          // wave 1: base = sum gfill[0..b)
        int l = tid - 64;
        int s = 0;
        for (int i = l; i < b; i += 64) s += gfill[i];
        #pragma unroll
        for (int off = 32; off > 0; off >>= 1) s += __shfl_down(s, off);
        if (l == 0) bbase_s = s;
    }
    for (int i = tid; i < cnt; i += 256) atomicAdd(&h4[grp][p[i] >> 17], 1);
    __syncthreads();
    if (tid < 64) {        // wave 0: totals, scan, per-group cursor bases
        int carry = 0;
        for (int base = 0; base < BKT; base += 64) {
            int idx = base + tid;
            int c0 = h4[0][idx], c1 = h4[1][idx], c2 = h4[2][idx], c3 = h4[3][idx];
            int v = c0 + c1 + c2 + c3;
            int s = v;
            #pragma unroll
            for (int off = 1; off < 64; off <<= 1) {
                int u = __shfl_up(s, off);
                if (tid >= off) s += u;
            }
            int ex = carry + s - v;
            hs[idx] = ex;
            tot[idx] = v;
            h4[0][idx] = ex;
            h4[1][idx] = ex + c0;
            h4[2][idx] = ex + c0 + c1;
            h4[3][idx] = ex + c0 + c1 + c2;
            carry += __shfl(s, 63);
        }
    }
    __syncthreads();
    int base = bbase_s;
    if (tid < BKT) {
        int node = b * BKT + tid;
        if (node < N) {
            rowptr[node] = base + hs[tid];
            dinv[node] = 1.0f / sqrtf((float)(tot[tid] + 1));
        }
    }
    if (b == 0 && tid == 0) rowptr[N] = E;
    __syncthreads();
    for (int i = tid; i < cnt; i += 256) {  // place via per-group cursors
        unsigned int u = p[i];
        int local = u >> 17;
        int pos = atomicAdd(&h4[grp][local], 1);
        col[base + pos] = (int)(u & 0x1FFFFu);
    }
}

// ---- input layer: t' = fp8( dinv_i * (x @ W_s) ) --------------------------

__global__ void in_gemm_kernel(const float* __restrict__ x, const float* __restrict__ W,
                               const float* __restrict__ dinv,
                               unsigned char* __restrict__ t8, int n) {
    int g = blockIdx.x * 256 + threadIdx.x;
    int i = g >> 6, c2 = g & 63;
    if (i >= n) return;
    float x0 = x[i * 3], x1 = x[i * 3 + 1], x2 = x[i * 3 + 2];
    float d = dinv[i];
    int c = c2 * 2;
    float v0 = d * (x0 * W[c]     + x1 * W[128 + c]     + x2 * W[256 + c]);
    float v1 = d * (x0 * W[c + 1] + x1 * W[128 + c + 1] + x2 * W[256 + c + 1]);
    unsigned int pk = __builtin_amdgcn_cvt_pk_fp8_f32(v0, v1, 0, false);
    ((unsigned short*)t8)[(size_t)i * 64 + c2] = (unsigned short)(pk & 0xFFFF);
}

// ---- shared GEMM pieces (16-row tile per wave) ----------------------------
// Ws points at global packed weights (L1/L2-hot, shared by all blocks).

__device__ __forceinline__ void gemm_regs16(const short8 af[4], const unsigned short* Ws,
                                            int lane, floatx4 acc[8]) {
    #pragma unroll
    for (int nt = 0; nt < 8; ++nt) acc[nt] = (floatx4){0.f, 0.f, 0.f, 0.f};
    #pragma unroll
    for (int kc = 0; kc < 4; ++kc) {
        #pragma unroll
        for (int nt = 0; nt < 8; ++nt) {
            short8 bf = *((const short8*)(Ws + ((kc * 8 + nt) * 64 + lane) * 8));
            acc[nt] = __builtin_amdgcn_mfma_f32_16x16x32_bf16(af[kc], bf, acc[nt], 0, 0, 0);
        }
    }
}

__device__ __forceinline__ void gemm_lds16(const unsigned short* Hs, const unsigned short* Ws,
                                           int wav, int lane, floatx4 acc[8]) {
    int quad = lane >> 4, mrow = lane & 15;
    short8 af[4];
    #pragma unroll
    for (int kc = 0; kc < 4; ++kc)
        af[kc] = ld_frag(Hs + (wav * 16 + mrow) * HS_STRIDE + (kc * 4 + quad) * 8);
    gemm_regs16(af, Ws, lane, acc);
}

__device__ __forceinline__ void relu_store_hs16(
        unsigned short* Hs, const float* __restrict__ bias,
        floatx4 acc[8], int wav, int lane) {
    int quad = lane >> 4, mrow = lane & 15;
    #pragma unroll
    for (int nt = 0; nt < 8; ++nt) {
        int colc = nt * 16 + mrow;
        float bcol = bias[colc];
        #pragma unroll
        for (int r = 0; r < 4; ++r) {
            int rowl = wav * 16 + quad * 4 + r;
            Hs[rowl * HS_STRIDE + colc] = f2bf(fmaxf(acc[nt][r] + bcol, 0.f));
        }
    }
}

// ---- aggregation phase (device fn): 128 nodes/block, 512 threads ----------
// Quarter-wave per node, 4 nodes sequential per quarter. rowptr hoisted;
// next-iteration col loads issued under current gather latency.

__device__ __forceinline__ void agg_to_hs(
        const unsigned char* __restrict__ t8, const int* __restrict__ rowptr,
        const int* __restrict__ col, const float* __restrict__ dinv,
        const float* __restrict__ bias, unsigned short* Hs, int n) {
    int tid = threadIdx.x;
    int lane = tid & 63;
    int q16 = lane >> 4;            // quarter (node) within wave
    int lq  = lane & 15;            // edge slot within half-round
    int oct = (lane >> 3) & 1;      // which of 2 rows this lane helps load
    int l8  = lane & 7;             // 16B chunk within row
    int qrow0 = (tid >> 4) * 4;     // local row base for this quarter (0..124)
    const float4* b4 = (const float4*)bias;

    int nd0 = blockIdx.x * 128 + qrow0;
    int bg[4], dg[4];
    #pragma unroll
    for (int it = 0; it < 4; ++it) {
        int node = nd0 + it; if (node >= n) node = n - 1;
        bg[it] = rowptr[node];
        dg[it] = rowptr[node + 1] - bg[it];
    }
    // preload col for it = 0
    int jv0 = (lq < dg[0])      ? col[bg[0] + lq]      : n;   // n = zero row
    int jv1 = (lq + 16 < dg[0]) ? col[bg[0] + 16 + lq] : n;

    for (int it = 0; it < 4; ++it) {
        int rowl = qrow0 + it;
        int node = nd0 + it; if (node >= n) node = n - 1;   // dup tail, benign
        floatx2 acc[8];                 // cols 16*l8 .. +16
        #pragma unroll
        for (int i = 0; i < 8; ++i) acc[i] = (floatx2){0.f, 0.f};

        // self row: independent, issue early
        uint4 s = ((const uint4*)(t8 + (size_t)node * 128))[l8];

        int deg = dg[it];
        // round 0 from preloaded jv
        uint4 v[16];
        #pragma unroll
        for (int q = 0; q < 8; ++q) {
            int j = __shfl(jv0, q16 * 16 + q * 2 + oct);
            v[q] = ((const uint4*)(t8 + (size_t)j * 128))[l8];
        }
        #pragma unroll
        for (int q = 0; q < 8; ++q) {
            int j = __shfl(jv1, q16 * 16 + q * 2 + oct);
            v[8 + q] = ((const uint4*)(t8 + (size_t)j * 128))[l8];
        }
        // prefetch next iteration's col while gathers are in flight
        int njv0 = n, njv1 = n;
        if (it < 3) {
            njv0 = (lq < dg[it + 1])      ? col[bg[it + 1] + lq]      : n;
            njv1 = (lq + 16 < dg[it + 1]) ? col[bg[it + 1] + 16 + lq] : n;
        }
        #pragma unroll
        for (int q = 0; q < 16; ++q) {
            acc[0] += __builtin_amdgcn_cvt_pk_f32_fp8(v[q].x, false);
            acc[1] += __builtin_amdgcn_cvt_pk_f32_fp8(v[q].x, true);
            acc[2] += __builtin_amdgcn_cvt_pk_f32_fp8(v[q].y, false);
            acc[3] += __builtin_amdgcn_cvt_pk_f32_fp8(v[q].y, true);
            acc[4] += __builtin_amdgcn_cvt_pk_f32_fp8(v[q].z, false);
            acc[5] += __builtin_amdgcn_cvt_pk_f32_fp8(v[q].z, true);
            acc[6] += __builtin_amdgcn_cvt_pk_f32_fp8(v[q].w, false);
            acc[7] += __builtin_amdgcn_cvt_pk_f32_fp8(v[q].w, true);
        }
        // rare extra rounds (deg > 32)
        for (int base = 32; base < deg; base += 32) {
            int m = deg - base;
            int a0 = (lq < m)      ? col[bg[it] + base + lq]      : n;
            int a1 = (lq + 16 < m) ? col[bg[it] + base + 16 + lq] : n;
            #pragma unroll
            for (int q = 0; q < 8; ++q) {
                int j = __shfl(a0, q16 * 16 + q * 2 + oct);
                v[q] = ((const uint4*)(t8 + (size_t)j * 128))[l8];
            }
            #pragma unroll
            for (int q = 0; q < 8; ++q) {
                int j = __shfl(a1, q16 * 16 + q * 2 + oct);
                v[8 + q] = ((const uint4*)(t8 + (size_t)j * 128))[l8];
            }
            #pragma unroll
            for (int q = 0; q < 16; ++q) {
                acc[0] += __builtin_amdgcn_cvt_pk_f32_fp8(v[q].x, false);
                acc[1] += __builtin_amdgcn_cvt_pk_f32_fp8(v[q].x, true);
                acc[2] += __builtin_amdgcn_cvt_pk_f32_fp8(v[q].y, false);
                acc[3] += __builtin_amdgcn_cvt_pk_f32_fp8(v[q].y, true);
                acc[4] += __builtin_amdgcn_cvt_pk_f32_fp8(v[q].z, false);
                acc[5] += __builtin_amdgcn_cvt_pk_f32_fp8(v[q].z, true);
                acc[6] += __builtin_amdgcn_cvt_pk_f32_fp8(v[q].w, false);
                acc[7] += __builtin_amdgcn_cvt_pk_f32_fp8(v[q].w, true);
            }
        }
        // cross-oct reduce
        #pragma unroll
        for (int i = 0; i < 8; ++i) {
            acc[i].x += __shfl_xor(acc[i].x, 8);
            acc[i].y += __shfl_xor(acc[i].y, 8);
        }
        // add self row
        acc[0] += __builtin_amdgcn_cvt_pk_f32_fp8(s.x, false);
        acc[1] += __builtin_amdgcn_cvt_pk_f32_fp8(s.x, true);
        acc[2] += __builtin_amdgcn_cvt_pk_f32_fp8(s.y, false);
        acc[3] += __builtin_amdgcn_cvt_pk_f32_fp8(s.y, true);
        acc[4] += __builtin_amdgcn_cvt_pk_f32_fp8(s.z, false);
        acc[5] += __builtin_amdgcn_cvt_pk_f32_fp8(s.z, true);
        acc[6] += __builtin_amdgcn_cvt_pk_f32_fp8(s.w, false);
        acc[7] += __builtin_amdgcn_cvt_pk_f32_fp8(s.w, true);

        float di = dinv[node];
        float o[16];
        #pragma unroll
        for (int k = 0; k < 4; ++k) {
            float4 bb = b4[l8 * 4 + k];
            o[k*4+0] = fmaxf(di * acc[k*2].x   + bb.x, 0.f);
            o[k*4+1] = fmaxf(di * acc[k*2].y   + bb.y, 0.f);
            o[k*4+2] = fmaxf(di * acc[k*2+1].x + bb.z, 0.f);
            o[k*4+3] = fmaxf(di * acc[k*2+1].y + bb.w, 0.f);
        }
        if (oct == 0) {                 // write bf16 row chunk to LDS
            unsigned short* hp = Hs + rowl * HS_STRIDE + l8 * 16;
            uint2 w;
            w.x = pk_bf(o[0],  o[1]);  w.y = pk_bf(o[2],  o[3]);
            *(uint2*)(hp)      = w;
            w.x = pk_bf(o[4],  o[5]);  w.y = pk_bf(o[6],  o[7]);
            *(uint2*)(hp + 4)  = w;
            w.x = pk_bf(o[8],  o[9]);  w.y = pk_bf(o[10], o[11]);
            *(uint2*)(hp + 8)  = w;
            w.x = pk_bf(o[12], o[13]); w.y = pk_bf(o[14], o[15]);
            *(uint2*)(hp + 12) = w;
        }
        jv0 = njv0; jv1 = njv1;
    }
}

// ---- fused agg + encoder GEMM: t8_out = fp8( dinv * (agg(t8_in) @ W) ) ----
// 512 threads / 8 waves; wave w owns Hs rows 16w..16w+15 (its own quarters
// wrote them) -> agg->gemm handoff needs no barrier.

__global__ __launch_bounds__(512, 4) void agg_gemm_kernel(
        const unsigned char* __restrict__ t8, const int* __restrict__ rowptr,
        const int* __restrict__ col, const float* __restrict__ dinv,
        const float* __restrict__ bias, const unsigned short* __restrict__ Wp,
        unsigned char* __restrict__ outp, int n) {
    __shared__ unsigned short Hs[128 * HS_STRIDE];
    agg_to_hs(t8, rowptr, col, dinv, bias, Hs, n);

    int tid = threadIdx.x;
    int wav = tid >> 6, lane = tid & 63;
    int quad = lane >> 4, mrow = lane & 15;
    int row0 = blockIdx.x * 128 + wav * 16;

    floatx4 acc[8];
    gemm_lds16(Hs, Wp, wav, lane, acc);

    int rbase = row0 + quad * 4;
    float dv[4];
    #pragma unroll
    for (int r = 0; r < 4; ++r)
        dv[r] = (rbase + r < n) ? dinv[rbase + r] : 0.f;
    #pragma unroll
    for (int nt = 0; nt < 8; ++nt) {
        int colc = nt * 16 + mrow;
        #pragma unroll
        for (int r = 0; r < 4; ++r) {
            int row = rbase + r;
            if (row < n)
                outp[(size_t)row * 128 + colc] = f2fp8(acc[nt][r] * dv[r]);
        }
    }
}

// ---- fused agg + decoder: agg -> GEMM(W_sd) -> 2x GEMM(W_md) -> proj+res --

__global__ __launch_bounds__(512, 4) void agg_dec_kernel(
        const unsigned char* __restrict__ t8, const int* __restrict__ rowptr,
        const int* __restrict__ col, const float* __restrict__ dinv,
        const float* __restrict__ bias,
        const unsigned short* __restrict__ Wp_sd, const float* __restrict__ b_sd,
        const unsigned short* __restrict__ Wp_md, const float* __restrict__ b_md,
        const float* __restrict__ W_ed, const float* __restrict__ b_ed,
        const float* __restrict__ x, float* __restrict__ out, int n) {
    __shared__ unsigned short Hs[128 * HS_STRIDE];
    agg_to_hs(t8, rowptr, col, dinv, bias, Hs, n);

    int tid = threadIdx.x;
    int wav = tid >> 6, lane = tid & 63;
    int quad = lane >> 4, mrow = lane & 15;
    int row0 = blockIdx.x * 128 + wav * 16;

    floatx4 acc[8];
    // stage 1: h @ W_sd
    gemm_lds16(Hs, Wp_sd, wav, lane, acc);
    relu_store_hs16(Hs, b_sd, acc, wav, lane);
    // stage 2: @ W_md (rows wave-private, no barrier)
    gemm_lds16(Hs, Wp_md, wav, lane, acc);
    relu_store_hs16(Hs, b_md, acc, wav, lane);
    // stage 3: @ W_md
    gemm_lds16(Hs, Wp_md, wav, lane, acc);

    // out-projection: relu(acc+b_md) @ W_ed + b_ed + x
    float wed[8][3];
    #pragma unroll
    for (int nt = 0; nt < 8; ++nt) {
        int c = nt * 16 + mrow;
        #pragma unroll
        for (int k = 0; k < 3; ++k) wed[nt][k] = W_ed[c * 3 + k];
    }
    #pragma unroll
    for (int r = 0; r < 4; ++r) {
        float s0 = 0.f, s1 = 0.f, s2 = 0.f;
        #pragma unroll
        for (int nt = 0; nt < 8; ++nt) {
            float v = fmaxf(acc[nt][r] + b_md[nt * 16 + mrow], 0.f);
            s0 += v * wed[nt][0]; s1 += v * wed[nt][1]; s2 += v * wed[nt][2];
        }
        #pragma unroll
        for (int off = 1; off < 16; off <<= 1) {
            s0 += __shfl_xor(s0, off);
            s1 += __shfl_xor(s1, off);
            s2 += __shfl_xor(s2, off);
        }
        if (mrow == 0) {
            int row = row0 + quad * 4 + r;
            if (row < n) {
                out[row * 3 + 0] = s0 + b_ed[0] + x[row * 3 + 0];
                out[row * 3 + 1] = s1 + b_ed[1] + x[row * 3 + 1];
                out[row * 3 + 2] = s2 + b_ed[2] + x[row * 3 + 2];
            }
        }
    }
}

// ---------------------------------------------------------------------------

extern "C" void kernel_launch(void* const* d_in, const int* in_sizes, int n_in,
                              void* d_out, int out_size, void* d_ws, size_t ws_size,
                              hipStream_t stream) {
    const float* x    = (const float*)d_in[0];
    const int*   ei   = (const int*)d_in[1];
    const float* W_s  = (const float*)d_in[2];
    const float* b_s  = (const float*)d_in[3];
    const float* W_m  = (const float*)d_in[4];
    const float* b_m  = (const float*)d_in[5];
    const float* W_e  = (const float*)d_in[6];
    const float* b_e  = (const float*)d_in[7];
    const float* W_sd = (const float*)d_in[8];
    const float* b_sd = (const float*)d_in[9];
    const float* W_md = (const float*)d_in[10];
    const float* b_md = (const float*)d_in[11];
    const float* W_ed = (const float*)d_in[12];
    const float* b_ed = (const float*)d_in[13];
    float* outp = (float*)d_out;

    const int N = in_sizes[0] / 3;
    const int E = in_sizes[1] / 2;
    const int* src = ei;
    const int* dst = ei + E;

    const int NB = (N + BKT - 1) / BKT;                  // 256-node buckets
    const int C  = (((E / NB) * 3 / 2) + 255) & ~255;    // segment cap, 1.5x mean

    char* p = (char*)d_ws;
    auto carve = [&](size_t bytes) {
        void* r = (void*)p;
        p += (bytes + 255) & ~(size_t)255;
        return r;
    };
    int*   rowptr = (int*)  carve((size_t)(N + 1) * 4);
    int*   col    = (int*)  carve((size_t)E * 4);
    float* dinv   = (float*)carve((size_t)N * 4);
    int*   gfill  = (int*)  carve((size_t)NB * 4);
    unsigned int* binbuf = (unsigned int*)carve((size_t)NB * C * 4);
    unsigned short* Wp_m  = (unsigned short*)carve(16384 * 2);
    unsigned short* Wp_e  = (unsigned short*)carve(16384 * 2);
    unsigned short* Wp_sd = (unsigned short*)carve(16384 * 2);
    unsigned short* Wp_md = (unsigned short*)carve(16384 * 2);
    unsigned char*  T8a = (unsigned char*) carve((size_t)(N + 1) * 128);   // +1 zero row
    unsigned char*  T8b = (unsigned char*) carve((size_t)(N + 1) * 128);   // ping-pong
    (void)ws_size;

    const int gBin = (E + BIN_CH - 1) / BIN_CH;
    const int gRow128 = (N + 127) / 128;

    // weight packs + buffer init (no deps)
    pack_kernel<<<32, 256, 0, stream>>>(W_m, W_e, W_sd, W_md, Wp_m, Wp_e, Wp_sd, Wp_md,
                                        gfill, T8a + (size_t)N * 128,
                                        T8b + (size_t)N * 128, NB);

    // graph build
    bin_kernel<<<gBin, 512, 0, stream>>>(src, dst, gfill, binbuf, NB, C, E);
    build_kernel<<<NB, 256, 0, stream>>>(binbuf, gfill, rowptr, dinv, col, NB, C, N, E);

    // encoder: t' in fp8; agg+GEMM fused, T8 ping-pong kills in-place race
    in_gemm_kernel<<<(N * 64 + 255) / 256, 256, 0, stream>>>(x, W_s, dinv, T8a, N);
    agg_gemm_kernel<<<gRow128, 512, 0, stream>>>(T8a, rowptr, col, dinv, b_s, Wp_m, T8b, N);
    agg_gemm_kernel<<<gRow128, 512, 0, stream>>>(T8b, rowptr, col, dinv, b_m, Wp_m, T8a, N);
    agg_gemm_kernel<<<gRow128, 512, 0, stream>>>(T8a, rowptr, col, dinv, b_m, Wp_e, T8b, N);

    // fused 4th agg + decoder
    agg_dec_kernel<<<gRow128, 512, 0, stream>>>(T8b, rowptr, col, dinv, b_e,
                                                Wp_sd, b_sd, Wp_md, b_md,
                                                W_ed, b_ed, x, outp, N);
}

// Round 5
// 385.960 us; speedup vs baseline: 1.0168x; 1.0168x over previous
//
#include <hip/hip_runtime.h>

// ---------------------------------------------------------------------------
// GCN encoder (4 conv layers, shared CSR graph) + 3-layer MLP decoder.
// Round 21: fix R20's spill regression (104 MB scratch writes — hoisted
// prefetch arrays blew the (512,4)=128 VGPR cap). Revert to R19's proven
// no-spill agg body (72 VGPR, on-demand col loads), and restore concurrency
// by halving the row-tile: 64 rows/block, 256 threads, grid 782->1563
// (occupancy cap 12.2 -> 24.4 waves/CU), agg depth 8->4. One __syncthreads
// between agg and GEMM (row ownership no longer wave-aligned); all 4 waves
// run 16-row GEMM tiles. Decoder stages stay wave-private after stage 1.
// ---------------------------------------------------------------------------

typedef __attribute__((ext_vector_type(8))) short short8;
typedef __attribute__((ext_vector_type(4))) float floatx4;
typedef __attribute__((ext_vector_type(2))) float floatx2;

#define BIN_CH 8192          // edges per bin block
#define NBMAX 512            // max buckets supported
#define BKT 256              // nodes per bucket
#define HS_STRIDE 68         // LDS row stride in ushorts (136 B)
#define ROWS 64              // rows per fused block

__device__ __forceinline__ unsigned short f2bf(float f) {
    unsigned int u = __float_as_uint(f);
    u += 0x7fffu + ((u >> 16) & 1u);          // round-to-nearest-even
    return (unsigned short)(u >> 16);
}
__device__ __forceinline__ unsigned int pk_bf(float a, float b) {
    return (unsigned int)f2bf(a) | ((unsigned int)f2bf(b) << 16);
}
__device__ __forceinline__ unsigned char f2fp8(float f) {
    return (unsigned char)(__builtin_amdgcn_cvt_pk_fp8_f32(f, f, 0, false) & 0xFF);
}
__device__ __forceinline__ short8 ld_frag(const unsigned short* p) {
    uint2 a = *(const uint2*)p;
    uint2 b = *(const uint2*)(p + 4);
    int4 v = make_int4((int)a.x, (int)a.y, (int)b.x, (int)b.y);
    return __builtin_bit_cast(short8, v);
}

// ---- weight pre-pack + buffer init (runs first) ---------------------------

__global__ void pack_kernel(const float* __restrict__ W0, const float* __restrict__ W1,
                            const float* __restrict__ W2, const float* __restrict__ W3,
                            unsigned short* __restrict__ P0, unsigned short* __restrict__ P1,
                            unsigned short* __restrict__ P2, unsigned short* __restrict__ P3,
                            int* __restrict__ gfill, unsigned char* __restrict__ t8zrowA,
                            unsigned char* __restrict__ t8zrowB, int NB) {
    if (blockIdx.x == 0) {                       // fold the memsets
        for (int i = threadIdx.x; i < NB; i += 256) gfill[i] = 0;
        if (threadIdx.x < 32) {
            ((unsigned int*)t8zrowA)[threadIdx.x] = 0;
            ((unsigned int*)t8zrowB)[threadIdx.x] = 0;
        }
    }
    int which = blockIdx.x >> 3;
    const float* W = which == 0 ? W0 : which == 1 ? W1 : which == 2 ? W2 : W3;
    unsigned short* P = which == 0 ? P0 : which == 1 ? P1 : which == 2 ? P2 : P3;
    int f = (blockIdx.x & 7) * 256 + threadIdx.x;
    int lane = f & 63, nt = (f >> 6) & 7, kc = f >> 9;
    int kbase = kc * 32 + (lane >> 4) * 8;
    int ncol = nt * 16 + (lane & 15);
    short8 frag;
    #pragma unroll
    for (int j = 0; j < 8; ++j)
        frag[j] = (short)f2bf(W[(size_t)(kbase + j) * 128 + ncol]);
    *((short8*)(P + (size_t)f * 8)) = frag;
}

// ---- graph build ----------------------------------------------------------
// entry = (d & 255) << 17 | src   (src < 2^17)

__global__ __launch_bounds__(512) void bin_kernel(
        const int* __restrict__ src, const int* __restrict__ dst,
        int* __restrict__ gfill, unsigned int* __restrict__ binbuf,
        int NB, int C, int E) {
    __shared__ int h4[4][NBMAX];     // per-group counts -> cursors
    __shared__ int start[NBMAX];
    __shared__ int tot[NBMAX];
    __shared__ int dstoff[NBMAX];
    int tid = threadIdx.x;
    int grp = tid >> 7;
    int e0 = blockIdx.x * BIN_CH;
    for (int i = tid; i < 4 * NBMAX; i += 512) ((int*)h4)[i] = 0;
    __syncthreads();
    for (int i = tid; i < BIN_CH; i += 512) {
        int e = e0 + i;
        if (e < E) atomicAdd(&h4[grp][dst[e] >> 8], 1);
    }
    __syncthreads();
    if (tid < 64) {        // wave 0: totals, exclusive scan, per-group bases
        int carry = 0;
        for (int base = 0; base < NB; base += 64) {
            int idx = base + tid;
            int c0 = 0, c1 = 0, c2 = 0, c3 = 0, v = 0;
            if (idx < NB) {
                c0 = h4[0][idx]; c1 = h4[1][idx];
                c2 = h4[2][idx]; c3 = h4[3][idx];
                v = c0 + c1 + c2 + c3;
            }
            int s = v;
            #pragma unroll
            for (int off = 1; off < 64; off <<= 1) {
                int u = __shfl_up(s, off);
                if (tid >= off) s += u;
            }
            if (idx < NB) {
                int ex = carry + s - v;
                start[idx] = ex;
                tot[idx] = v;
                h4[0][idx] = ex;
                h4[1][idx] = ex + c0;
                h4[2][idx] = ex + c0 + c1;
                h4[3][idx] = ex + c0 + c1 + c2;
            }
            carry += __shfl(s, 63);
        }
    }
    __syncthreads();
    for (int i = tid; i < NB; i += 512) {   // reserve global runs
        int cnt = tot[i];
        int g = cnt ? atomicAdd(&gfill[i], cnt) : 0;
        dstoff[i] = g - start[i];
    }
    __syncthreads();
    for (int i = tid; i < BIN_CH; i += 512) {
        int e = e0 + i;
        if (e >= E) continue;
        int d = dst[e];
        int b = d >> 8;
        int slot = atomicAdd(&h4[grp][b], 1);         // block-local rank
        int gidx = b * C + dstoff[b] + slot;
        if (gidx < (b + 1) * C)
            binbuf[gidx] = (unsigned int)src[e] | ((unsigned int)(d & 255) << 17);
    }
}

// one block per bucket: split hist(4x256) -> scan -> rowptr/dinv -> place.
// Bucket base computed in-kernel (wave 1 sums gfill[0..b)).
__global__ __launch_bounds__(256) void build_kernel(
        const unsigned int* __restrict__ binbuf, const int* __restrict__ gfill,
        int* __restrict__ rowptr, float* __restrict__ dinv, int* __restrict__ col,
        int NB, int C, int N, int E) {
    __shared__ int h4[4][BKT];       // per-group counts -> cursors
    __shared__ int hs[BKT];          // exclusive scan of totals
    __shared__ int tot[BKT];
    __shared__ int bbase_s;
    int b = blockIdx.x, tid = threadIdx.x;
    int grp = tid >> 6;
    int cnt = gfill[b];
    const unsigned int* p = binbuf + (size_t)b * C;
    for (int i = tid; i < 4 * BKT; i += 256) ((int*)h4)[i] = 0;
    __syncthreads();
    if (tid >= 64 && tid < 128) {          // wave 1: base = sum gfill[0..b)
        int l = tid - 64;
        int s = 0;
        for (int i = l; i < b; i += 64) s += gfill[i];
        #pragma unroll
        for (int off = 32; off > 0; off >>= 1) s += __shfl_down(s, off);
        if (l == 0) bbase_s = s;
    }
    for (int i = tid; i < cnt; i += 256) atomicAdd(&h4[grp][p[i] >> 17], 1);
    __syncthreads();
    if (tid < 64) {        // wave 0: totals, scan, per-group cursor bases
        int carry = 0;
        for (int base = 0; base < BKT; base += 64) {
            int idx = base + tid;
            int c0 = h4[0][idx], c1 = h4[1][idx], c2 = h4[2][idx], c3 = h4[3][idx];
            int v = c0 + c1 + c2 + c3;
            int s = v;
            #pragma unroll
            for (int off = 1; off < 64; off <<= 1) {
                int u = __shfl_up(s, off);
                if (tid >= off) s += u;
            }
            int ex = carry + s - v;
            hs[idx] = ex;
            tot[idx] = v;
            h4[0][idx] = ex;
            h4[1][idx] = ex + c0;
            h4[2][idx] = ex + c0 + c1;
            h4[3][idx] = ex + c0 + c1 + c2;
            carry += __shfl(s, 63);
        }
    }
    __syncthreads();
    int base = bbase_s;
    if (tid < BKT) {
        int node = b * BKT + tid;
        if (node < N) {
            rowptr[node] = base + hs[tid];
            dinv[node] = 1.0f / sqrtf((float)(tot[tid] + 1));
        }
    }
    if (b == 0 && tid == 0) rowptr[N] = E;
    __syncthreads();
    for (int i = tid; i < cnt; i += 256) {  // place via per-group cursors
        unsigned int u = p[i];
        int local = u >> 17;
        int pos = atomicAdd(&h4[grp][local], 1);
        col[base + pos] = (int)(u & 0x1FFFFu);
    }
}

// ---- input layer: t' = fp8( dinv_i * (x @ W_s) ) --------------------------

__global__ void in_gemm_kernel(const float* __restrict__ x, const float* __restrict__ W,
                               const float* __restrict__ dinv,
                               unsigned char* __restrict__ t8, int n) {
    int g = blockIdx.x * 256 + threadIdx.x;
    int i = g >> 6, c2 = g & 63;
    if (i >= n) return;
    float x0 = x[i * 3], x1 = x[i * 3 + 1], x2 = x[i * 3 + 2];
    float d = dinv[i];
    int c = c2 * 2;
    float v0 = d * (x0 * W[c]     + x1 * W[128 + c]     + x2 * W[256 + c]);
    float v1 = d * (x0 * W[c + 1] + x1 * W[128 + c + 1] + x2 * W[256 + c + 1]);
    unsigned int pk = __builtin_amdgcn_cvt_pk_fp8_f32(v0, v1, 0, false);
    ((unsigned short*)t8)[(size_t)i * 64 + c2] = (unsigned short)(pk & 0xFFFF);
}

// ---- shared GEMM pieces (16-row tile per wave) ----------------------------
// Ws points at global packed weights (L1/L2-hot, shared by all blocks).

__device__ __forceinline__ void gemm_regs16(const short8 af[4], const unsigned short* Ws,
                                            int lane, floatx4 acc[8]) {
    #pragma unroll
    for (int nt = 0; nt < 8; ++nt) acc[nt] = (floatx4){0.f, 0.f, 0.f, 0.f};
    #pragma unroll
    for (int kc = 0; kc < 4; ++kc) {
        #pragma unroll
        for (int nt = 0; nt < 8; ++nt) {
            short8 bf = *((const short8*)(Ws + ((kc * 8 + nt) * 64 + lane) * 8));
            acc[nt] = __builtin_amdgcn_mfma_f32_16x16x32_bf16(af[kc], bf, acc[nt], 0, 0, 0);
        }
    }
}

__device__ __forceinline__ void gemm_lds16(const unsigned short* Hs, const unsigned short* Ws,
                                           int wav, int lane, floatx4 acc[8]) {
    int quad = lane >> 4, mrow = lane & 15;
    short8 af[4];
    #pragma unroll
    for (int kc = 0; kc < 4; ++kc)
        af[kc] = ld_frag(Hs + (wav * 16 + mrow) * HS_STRIDE + (kc * 4 + quad) * 8);
    gemm_regs16(af, Ws, lane, acc);
}

__device__ __forceinline__ void relu_store_hs16(
        unsigned short* Hs, const float* __restrict__ bias,
        floatx4 acc[8], int wav, int lane) {
    int quad = lane >> 4, mrow = lane & 15;
    #pragma unroll
    for (int nt = 0; nt < 8; ++nt) {
        int colc = nt * 16 + mrow;
        float bcol = bias[colc];
        #pragma unroll
        for (int r = 0; r < 4; ++r) {
            int rowl = wav * 16 + quad * 4 + r;
            Hs[rowl * HS_STRIDE + colc] = f2bf(fmaxf(acc[nt][r] + bcol, 0.f));
        }
    }
}

// ---- aggregation phase (device fn): 64 nodes/block, 256 threads -----------
// Quarter-wave per node, 4 nodes sequential per quarter. R19's proven
// no-spill body: on-demand col loads, no cross-iteration register state.

__device__ __forceinline__ void agg_to_hs(
        const unsigned char* __restrict__ t8, const int* __restrict__ rowptr,
        const int* __restrict__ col, const float* __restrict__ dinv,
        const float* __restrict__ bias, unsigned short* Hs, int n) {
    int tid = threadIdx.x;
    int lane = tid & 63;
    int q16 = lane >> 4;            // quarter (node) within wave
    int lq  = lane & 15;            // edge slot within half-round
    int oct = (lane >> 3) & 1;      // which of 2 rows this lane helps load
    int l8  = lane & 7;             // 16B chunk within row
    int qrow0 = (tid >> 4) * 4;     // local row base for this quarter (0..60)
    const float4* b4 = (const float4*)bias;

    for (int it = 0; it < 4; ++it) {
        int rowl = qrow0 + it;
        int node = blockIdx.x * ROWS + rowl;
        if (node >= n) node = n - 1;    // dup work in tail, benign
        floatx2 acc[8];                 // cols 16*l8 .. +16
        #pragma unroll
        for (int i = 0; i < 8; ++i) acc[i] = (floatx2){0.f, 0.f};

        int beg = rowptr[node];
        int deg = rowptr[node + 1] - beg;
        for (int base = 0; base < deg; base += 32) {
            int m = deg - base;
            int jv0 = (lq < m)      ? col[beg + base + lq]      : n;   // n = zero row
            int jv1 = (lq + 16 < m) ? col[beg + base + 16 + lq] : n;
            uint4 v[16];
            #pragma unroll
            for (int q = 0; q < 8; ++q) {
                int j = __shfl(jv0, q16 * 16 + q * 2 + oct);
                v[q] = ((const uint4*)(t8 + (size_t)j * 128))[l8];
            }
            #pragma unroll
            for (int q = 0; q < 8; ++q) {
                int j = __shfl(jv1, q16 * 16 + q * 2 + oct);
                v[8 + q] = ((const uint4*)(t8 + (size_t)j * 128))[l8];
            }
            #pragma unroll
            for (int q = 0; q < 16; ++q) {
                acc[0] += __builtin_amdgcn_cvt_pk_f32_fp8(v[q].x, false);
                acc[1] += __builtin_amdgcn_cvt_pk_f32_fp8(v[q].x, true);
                acc[2] += __builtin_amdgcn_cvt_pk_f32_fp8(v[q].y, false);
                acc[3] += __builtin_amdgcn_cvt_pk_f32_fp8(v[q].y, true);
                acc[4] += __builtin_amdgcn_cvt_pk_f32_fp8(v[q].z, false);
                acc[5] += __builtin_amdgcn_cvt_pk_f32_fp8(v[q].z, true);
                acc[6] += __builtin_amdgcn_cvt_pk_f32_fp8(v[q].w, false);
                acc[7] += __builtin_amdgcn_cvt_pk_f32_fp8(v[q].w, true);
            }
        }
        #pragma unroll
        for (int i = 0; i < 8; ++i) {
            acc[i].x += __shfl_xor(acc[i].x, 8);
            acc[i].y += __shfl_xor(acc[i].y, 8);
        }
        uint4 s = ((const uint4*)(t8 + (size_t)node * 128))[l8];
        acc[0] += __builtin_amdgcn_cvt_pk_f32_fp8(s.x, false);
        acc[1] += __builtin_amdgcn_cvt_pk_f32_fp8(s.x, true);
        acc[2] += __builtin_amdgcn_cvt_pk_f32_fp8(s.y, false);
        acc[3] += __builtin_amdgcn_cvt_pk_f32_fp8(s.y, true);
        acc[4] += __builtin_amdgcn_cvt_pk_f32_fp8(s.z, false);
        acc[5] += __builtin_amdgcn_cvt_pk_f32_fp8(s.z, true);
        acc[6] += __builtin_amdgcn_cvt_pk_f32_fp8(s.w, false);
        acc[7] += __builtin_amdgcn_cvt_pk_f32_fp8(s.w, true);

        float di = dinv[node];
        float o[16];
        #pragma unroll
        for (int k = 0; k < 4; ++k) {
            float4 bb = b4[l8 * 4 + k];
            o[k*4+0] = fmaxf(di * acc[k*2].x   + bb.x, 0.f);
            o[k*4+1] = fmaxf(di * acc[k*2].y   + bb.y, 0.f);
            o[k*4+2] = fmaxf(di * acc[k*2+1].x + bb.z, 0.f);
            o[k*4+3] = fmaxf(di * acc[k*2+1].y + bb.w, 0.f);
        }
        if (oct == 0) {                 // write bf16 row chunk to LDS
            unsigned short* hp = Hs + rowl * HS_STRIDE + l8 * 16;
            uint2 w;
            w.x = pk_bf(o[0],  o[1]);  w.y = pk_bf(o[2],  o[3]);
            *(uint2*)(hp)      = w;
            w.x = pk_bf(o[4],  o[5]);  w.y = pk_bf(o[6],  o[7]);
            *(uint2*)(hp + 4)  = w;
            w.x = pk_bf(o[8],  o[9]);  w.y = pk_bf(o[10], o[11]);
            *(uint2*)(hp + 8)  = w;
            w.x = pk_bf(o[12], o[13]); w.y = pk_bf(o[14], o[15]);
            *(uint2*)(hp + 12) = w;
        }
    }
}

// ---- fused agg + encoder GEMM: t8_out = fp8( dinv * (agg(t8_in) @ W) ) ----
// 64 rows/block. One barrier between agg and GEMM (row ownership crosses
// waves); all 4 waves then run independent 16-row GEMM tiles.

__global__ __launch_bounds__(256, 4) void agg_gemm_kernel(
        const unsigned char* __restrict__ t8, const int* __restrict__ rowptr,
        const int* __restrict__ col, const float* __restrict__ dinv,
        const float* __restrict__ bias, const unsigned short* __restrict__ Wp,
        unsigned char* __restrict__ outp, int n) {
    __shared__ unsigned short Hs[ROWS * HS_STRIDE];
    agg_to_hs(t8, rowptr, col, dinv, bias, Hs, n);
    __syncthreads();

    int tid = threadIdx.x;
    int wav = tid >> 6, lane = tid & 63;
    int quad = lane >> 4, mrow = lane & 15;
    int row0 = blockIdx.x * ROWS + wav * 16;

    floatx4 acc[8];
    gemm_lds16(Hs, Wp, wav, lane, acc);

    int rbase = row0 + quad * 4;
    float dv[4];
    #pragma unroll
    for (int r = 0; r < 4; ++r)
        dv[r] = (rbase + r < n) ? dinv[rbase + r] : 0.f;
    #pragma unroll
    for (int nt = 0; nt < 8; ++nt) {
        int colc = nt * 16 + mrow;
        #pragma unroll
        for (int r = 0; r < 4; ++r) {
            int row = rbase + r;
            if (row < n)
                outp[(size_t)row * 128 + colc] = f2fp8(acc[nt][r] * dv[r]);
        }
    }
}

// ---- fused agg + decoder: agg -> GEMM(W_sd) -> 2x GEMM(W_md) -> proj+res --
// Stages 2/3 are wave-private (each wave reads/writes its own 16-row tile).

__global__ __launch_bounds__(256, 4) void agg_dec_kernel(
        const unsigned char* __restrict__ t8, const int* __restrict__ rowptr,
        const int* __restrict__ col, const float* __restrict__ dinv,
        const float* __restrict__ bias,
        const unsigned short* __restrict__ Wp_sd, const float* __restrict__ b_sd,
        const unsigned short* __restrict__ Wp_md, const float* __restrict__ b_md,
        const float* __restrict__ W_ed, const float* __restrict__ b_ed,
        const float* __restrict__ x, float* __restrict__ out, int n) {
    __shared__ unsigned short Hs[ROWS * HS_STRIDE];
    agg_to_hs(t8, rowptr, col, dinv, bias, Hs, n);
    __syncthreads();

    int tid = threadIdx.x;
    int wav = tid >> 6, lane = tid & 63;
    int quad = lane >> 4, mrow = lane & 15;
    int row0 = blockIdx.x * ROWS + wav * 16;

    floatx4 acc[8];
    // stage 1: h @ W_sd
    gemm_lds16(Hs, Wp_sd, wav, lane, acc);
    relu_store_hs16(Hs, b_sd, acc, wav, lane);
    // stage 2: @ W_md (16-row tile wave-private from here on)
    gemm_lds16(Hs, Wp_md, wav, lane, acc);
    relu_store_hs16(Hs, b_md, acc, wav, lane);
    // stage 3: @ W_md
    gemm_lds16(Hs, Wp_md, wav, lane, acc);

    // out-projection: relu(acc+b_md) @ W_ed + b_ed + x
    float wed[8][3];
    #pragma unroll
    for (int nt = 0; nt < 8; ++nt) {
        int c = nt * 16 + mrow;
        #pragma unroll
        for (int k = 0; k < 3; ++k) wed[nt][k] = W_ed[c * 3 + k];
    }
    #pragma unroll
    for (int r = 0; r < 4; ++r) {
        float s0 = 0.f, s1 = 0.f, s2 = 0.f;
        #pragma unroll
        for (int nt = 0; nt < 8; ++nt) {
            float v = fmaxf(acc[nt][r] + b_md[nt * 16 + mrow], 0.f);
            s0 += v * wed[nt][0]; s1 += v * wed[nt][1]; s2 += v * wed[nt][2];
        }
        #pragma unroll
        for (int off = 1; off < 16; off <<= 1) {
            s0 += __shfl_xor(s0, off);
            s1 += __shfl_xor(s1, off);
            s2 += __shfl_xor(s2, off);
        }
        if (mrow == 0) {
            int row = row0 + quad * 4 + r;
            if (row < n) {
                out[row * 3 + 0] = s0 + b_ed[0] + x[row * 3 + 0];
                out[row * 3 + 1] = s1 + b_ed[1] + x[row * 3 + 1];
                out[row * 3 + 2] = s2 + b_ed[2] + x[row * 3 + 2];
            }
        }
    }
}

// ---------------------------------------------------------------------------

extern "C" void kernel_launch(void* const* d_in, const int* in_sizes, int n_in,
                              void* d_out, int out_size, void* d_ws, size_t ws_size,
                              hipStream_t stream) {
    const float* x    = (const float*)d_in[0];
    const int*   ei   = (const int*)d_in[1];
    const float* W_s  = (const float*)d_in[2];
    const float* b_s  = (const float*)d_in[3];
    const float* W_m  = (const float*)d_in[4];
    const float* b_m  = (const float*)d_in[5];
    const float* W_e  = (const float*)d_in[6];
    const float* b_e  = (const float*)d_in[7];
    const float* W_sd = (const float*)d_in[8];
    const float* b_sd = (const float*)d_in[9];
    const float* W_md = (const float*)d_in[10];
    const float* b_md = (const float*)d_in[11];
    const float* W_ed = (const float*)d_in[12];
    const float* b_ed = (const float*)d_in[13];
    float* outp = (float*)d_out;

    const int N = in_sizes[0] / 3;
    const int E = in_sizes[1] / 2;
    const int* src = ei;
    const int* dst = ei + E;

    const int NB = (N + BKT - 1) / BKT;                  // 256-node buckets
    const int C  = (((E / NB) * 3 / 2) + 255) & ~255;    // segment cap, 1.5x mean

    char* p = (char*)d_ws;
    auto carve = [&](size_t bytes) {
        void* r = (void*)p;
        p += (bytes + 255) & ~(size_t)255;
        return r;
    };
    int*   rowptr = (int*)  carve((size_t)(N + 1) * 4);
    int*   col    = (int*)  carve((size_t)E * 4);
    float* dinv   = (float*)carve((size_t)N * 4);
    int*   gfill  = (int*)  carve((size_t)NB * 4);
    unsigned int* binbuf = (unsigned int*)carve((size_t)NB * C * 4);
    unsigned short* Wp_m  = (unsigned short*)carve(16384 * 2);
    unsigned short* Wp_e  = (unsigned short*)carve(16384 * 2);
    unsigned short* Wp_sd = (unsigned short*)carve(16384 * 2);
    unsigned short* Wp_md = (unsigned short*)carve(16384 * 2);
    unsigned char*  T8a = (unsigned char*) carve((size_t)(N + 1) * 128);   // +1 zero row
    unsigned char*  T8b = (unsigned char*) carve((size_t)(N + 1) * 128);   // ping-pong
    (void)ws_size;

    const int gBin = (E + BIN_CH - 1) / BIN_CH;
    const int gRow64 = (N + ROWS - 1) / ROWS;

    // weight packs + buffer init (no deps)
    pack_kernel<<<32, 256, 0, stream>>>(W_m, W_e, W_sd, W_md, Wp_m, Wp_e, Wp_sd, Wp_md,
                                        gfill, T8a + (size_t)N * 128,
                                        T8b + (size_t)N * 128, NB);

    // graph build
    bin_kernel<<<gBin, 512, 0, stream>>>(src, dst, gfill, binbuf, NB, C, E);
    build_kernel<<<NB, 256, 0, stream>>>(binbuf, gfill, rowptr, dinv, col, NB, C, N, E);

    // encoder: t' in fp8; agg+GEMM fused, T8 ping-pong kills in-place race
    in_gemm_kernel<<<(N * 64 + 255) / 256, 256, 0, stream>>>(x, W_s, dinv, T8a, N);
    agg_gemm_kernel<<<gRow64, 256, 0, stream>>>(T8a, rowptr, col, dinv, b_s, Wp_m, T8b, N);
    agg_gemm_kernel<<<gRow64, 256, 0, stream>>>(T8b, rowptr, col, dinv, b_m, Wp_m, T8a, N);
    agg_gemm_kernel<<<gRow64, 256, 0, stream>>>(T8a, rowptr, col, dinv, b_m, Wp_e, T8b, N);

    // fused 4th agg + decoder
    agg_dec_kernel<<<gRow64, 256, 0, stream>>>(T8b, rowptr, col, dinv, b_e,
                                               Wp_sd, b_sd, Wp_md, b_md,
                                               W_ed, b_ed, x, outp, N);
}

// Round 6
// 380.188 us; speedup vs baseline: 1.0322x; 1.0152x over previous
//
#include <hip/hip_runtime.h>

// ---------------------------------------------------------------------------
// GCN encoder (4 conv layers, shared CSR graph) + 3-layer MLP decoder.
// Round 22: spill root-cause fix. R20/R21 both spilled (~100 MB scratch
// writes) because __launch_bounds__ min-waves=4 capped VGPR budget at 128 —
// too small for the fused agg(v[16] live)+GEMM body. R19's clean compile
// was (256,3) = 170 VGPR budget, 72 used, 0 spill. This round: identical to
// R21 (ROWS=64, grid 1563, depth-4 agg) but launch_bounds (256,3).
// Occupancy then grid-capped ~24 waves/CU (vs R19's 12.2 structural cap).
// ---------------------------------------------------------------------------

typedef __attribute__((ext_vector_type(8))) short short8;
typedef __attribute__((ext_vector_type(4))) float floatx4;
typedef __attribute__((ext_vector_type(2))) float floatx2;

#define BIN_CH 8192          // edges per bin block
#define NBMAX 512            // max buckets supported
#define BKT 256              // nodes per bucket
#define HS_STRIDE 68         // LDS row stride in ushorts (136 B)
#define ROWS 64              // rows per fused block

__device__ __forceinline__ unsigned short f2bf(float f) {
    unsigned int u = __float_as_uint(f);
    u += 0x7fffu + ((u >> 16) & 1u);          // round-to-nearest-even
    return (unsigned short)(u >> 16);
}
__device__ __forceinline__ unsigned int pk_bf(float a, float b) {
    return (unsigned int)f2bf(a) | ((unsigned int)f2bf(b) << 16);
}
__device__ __forceinline__ unsigned char f2fp8(float f) {
    return (unsigned char)(__builtin_amdgcn_cvt_pk_fp8_f32(f, f, 0, false) & 0xFF);
}
__device__ __forceinline__ short8 ld_frag(const unsigned short* p) {
    uint2 a = *(const uint2*)p;
    uint2 b = *(const uint2*)(p + 4);
    int4 v = make_int4((int)a.x, (int)a.y, (int)b.x, (int)b.y);
    return __builtin_bit_cast(short8, v);
}

// ---- weight pre-pack + buffer init (runs first) ---------------------------

__global__ void pack_kernel(const float* __restrict__ W0, const float* __restrict__ W1,
                            const float* __restrict__ W2, const float* __restrict__ W3,
                            unsigned short* __restrict__ P0, unsigned short* __restrict__ P1,
                            unsigned short* __restrict__ P2, unsigned short* __restrict__ P3,
                            int* __restrict__ gfill, unsigned char* __restrict__ t8zrowA,
                            unsigned char* __restrict__ t8zrowB, int NB) {
    if (blockIdx.x == 0) {                       // fold the memsets
        for (int i = threadIdx.x; i < NB; i += 256) gfill[i] = 0;
        if (threadIdx.x < 32) {
            ((unsigned int*)t8zrowA)[threadIdx.x] = 0;
            ((unsigned int*)t8zrowB)[threadIdx.x] = 0;
        }
    }
    int which = blockIdx.x >> 3;
    const float* W = which == 0 ? W0 : which == 1 ? W1 : which == 2 ? W2 : W3;
    unsigned short* P = which == 0 ? P0 : which == 1 ? P1 : which == 2 ? P2 : P3;
    int f = (blockIdx.x & 7) * 256 + threadIdx.x;
    int lane = f & 63, nt = (f >> 6) & 7, kc = f >> 9;
    int kbase = kc * 32 + (lane >> 4) * 8;
    int ncol = nt * 16 + (lane & 15);
    short8 frag;
    #pragma unroll
    for (int j = 0; j < 8; ++j)
        frag[j] = (short)f2bf(W[(size_t)(kbase + j) * 128 + ncol]);
    *((short8*)(P + (size_t)f * 8)) = frag;
}

// ---- graph build ----------------------------------------------------------
// entry = (d & 255) << 17 | src   (src < 2^17)

__global__ __launch_bounds__(512) void bin_kernel(
        const int* __restrict__ src, const int* __restrict__ dst,
        int* __restrict__ gfill, unsigned int* __restrict__ binbuf,
        int NB, int C, int E) {
    __shared__ int h4[4][NBMAX];     // per-group counts -> cursors
    __shared__ int start[NBMAX];
    __shared__ int tot[NBMAX];
    __shared__ int dstoff[NBMAX];
    int tid = threadIdx.x;
    int grp = tid >> 7;
    int e0 = blockIdx.x * BIN_CH;
    for (int i = tid; i < 4 * NBMAX; i += 512) ((int*)h4)[i] = 0;
    __syncthreads();
    for (int i = tid; i < BIN_CH; i += 512) {
        int e = e0 + i;
        if (e < E) atomicAdd(&h4[grp][dst[e] >> 8], 1);
    }
    __syncthreads();
    if (tid < 64) {        // wave 0: totals, exclusive scan, per-group bases
        int carry = 0;
        for (int base = 0; base < NB; base += 64) {
            int idx = base + tid;
            int c0 = 0, c1 = 0, c2 = 0, c3 = 0, v = 0;
            if (idx < NB) {
                c0 = h4[0][idx]; c1 = h4[1][idx];
                c2 = h4[2][idx]; c3 = h4[3][idx];
                v = c0 + c1 + c2 + c3;
            }
            int s = v;
            #pragma unroll
            for (int off = 1; off < 64; off <<= 1) {
                int u = __shfl_up(s, off);
                if (tid >= off) s += u;
            }
            if (idx < NB) {
                int ex = carry + s - v;
                start[idx] = ex;
                tot[idx] = v;
                h4[0][idx] = ex;
                h4[1][idx] = ex + c0;
                h4[2][idx] = ex + c0 + c1;
                h4[3][idx] = ex + c0 + c1 + c2;
            }
            carry += __shfl(s, 63);
        }
    }
    __syncthreads();
    for (int i = tid; i < NB; i += 512) {   // reserve global runs
        int cnt = tot[i];
        int g = cnt ? atomicAdd(&gfill[i], cnt) : 0;
        dstoff[i] = g - start[i];
    }
    __syncthreads();
    for (int i = tid; i < BIN_CH; i += 512) {
        int e = e0 + i;
        if (e >= E) continue;
        int d = dst[e];
        int b = d >> 8;
        int slot = atomicAdd(&h4[grp][b], 1);         // block-local rank
        int gidx = b * C + dstoff[b] + slot;
        if (gidx < (b + 1) * C)
            binbuf[gidx] = (unsigned int)src[e] | ((unsigned int)(d & 255) << 17);
    }
}

// one block per bucket: split hist(4x256) -> scan -> rowptr/dinv -> place.
// Bucket base computed in-kernel (wave 1 sums gfill[0..b)).
__global__ __launch_bounds__(256) void build_kernel(
        const unsigned int* __restrict__ binbuf, const int* __restrict__ gfill,
        int* __restrict__ rowptr, float* __restrict__ dinv, int* __restrict__ col,
        int NB, int C, int N, int E) {
    __shared__ int h4[4][BKT];       // per-group counts -> cursors
    __shared__ int hs[BKT];          // exclusive scan of totals
    __shared__ int tot[BKT];
    __shared__ int bbase_s;
    int b = blockIdx.x, tid = threadIdx.x;
    int grp = tid >> 6;
    int cnt = gfill[b];
    const unsigned int* p = binbuf + (size_t)b * C;
    for (int i = tid; i < 4 * BKT; i += 256) ((int*)h4)[i] = 0;
    __syncthreads();
    if (tid >= 64 && tid < 128) {          // wave 1: base = sum gfill[0..b)
        int l = tid - 64;
        int s = 0;
        for (int i = l; i < b; i += 64) s += gfill[i];
        #pragma unroll
        for (int off = 32; off > 0; off >>= 1) s += __shfl_down(s, off);
        if (l == 0) bbase_s = s;
    }
    for (int i = tid; i < cnt; i += 256) atomicAdd(&h4[grp][p[i] >> 17], 1);
    __syncthreads();
    if (tid < 64) {        // wave 0: totals, scan, per-group cursor bases
        int carry = 0;
        for (int base = 0; base < BKT; base += 64) {
            int idx = base + tid;
            int c0 = h4[0][idx], c1 = h4[1][idx], c2 = h4[2][idx], c3 = h4[3][idx];
            int v = c0 + c1 + c2 + c3;
            int s = v;
            #pragma unroll
            for (int off = 1; off < 64; off <<= 1) {
                int u = __shfl_up(s, off);
                if (tid >= off) s += u;
            }
            int ex = carry + s - v;
            hs[idx] = ex;
            tot[idx] = v;
            h4[0][idx] = ex;
            h4[1][idx] = ex + c0;
            h4[2][idx] = ex + c0 + c1;
            h4[3][idx] = ex + c0 + c1 + c2;
            carry += __shfl(s, 63);
        }
    }
    __syncthreads();
    int base = bbase_s;
    if (tid < BKT) {
        int node = b * BKT + tid;
        if (node < N) {
            rowptr[node] = base + hs[tid];
            dinv[node] = 1.0f / sqrtf((float)(tot[tid] + 1));
        }
    }
    if (b == 0 && tid == 0) rowptr[N] = E;
    __syncthreads();
    for (int i = tid; i < cnt; i += 256) {  // place via per-group cursors
        unsigned int u = p[i];
        int local = u >> 17;
        int pos = atomicAdd(&h4[grp][local], 1);
        col[base + pos] = (int)(u & 0x1FFFFu);
    }
}

// ---- input layer: t' = fp8( dinv_i * (x @ W_s) ) --------------------------

__global__ void in_gemm_kernel(const float* __restrict__ x, const float* __restrict__ W,
                               const float* __restrict__ dinv,
                               unsigned char* __restrict__ t8, int n) {
    int g = blockIdx.x * 256 + threadIdx.x;
    int i = g >> 6, c2 = g & 63;
    if (i >= n) return;
    float x0 = x[i * 3], x1 = x[i * 3 + 1], x2 = x[i * 3 + 2];
    float d = dinv[i];
    int c = c2 * 2;
    float v0 = d * (x0 * W[c]     + x1 * W[128 + c]     + x2 * W[256 + c]);
    float v1 = d * (x0 * W[c + 1] + x1 * W[128 + c + 1] + x2 * W[256 + c + 1]);
    unsigned int pk = __builtin_amdgcn_cvt_pk_fp8_f32(v0, v1, 0, false);
    ((unsigned short*)t8)[(size_t)i * 64 + c2] = (unsigned short)(pk & 0xFFFF);
}

// ---- shared GEMM pieces (16-row tile per wave) ----------------------------
// Ws points at global packed weights (L1/L2-hot, shared by all blocks).

__device__ __forceinline__ void gemm_regs16(const short8 af[4], const unsigned short* Ws,
                                            int lane, floatx4 acc[8]) {
    #pragma unroll
    for (int nt = 0; nt < 8; ++nt) acc[nt] = (floatx4){0.f, 0.f, 0.f, 0.f};
    #pragma unroll
    for (int kc = 0; kc < 4; ++kc) {
        #pragma unroll
        for (int nt = 0; nt < 8; ++nt) {
            short8 bf = *((const short8*)(Ws + ((kc * 8 + nt) * 64 + lane) * 8));
            acc[nt] = __builtin_amdgcn_mfma_f32_16x16x32_bf16(af[kc], bf, acc[nt], 0, 0, 0);
        }
    }
}

__device__ __forceinline__ void gemm_lds16(const unsigned short* Hs, const unsigned short* Ws,
                                           int wav, int lane, floatx4 acc[8]) {
    int quad = lane >> 4, mrow = lane & 15;
    short8 af[4];
    #pragma unroll
    for (int kc = 0; kc < 4; ++kc)
        af[kc] = ld_frag(Hs + (wav * 16 + mrow) * HS_STRIDE + (kc * 4 + quad) * 8);
    gemm_regs16(af, Ws, lane, acc);
}

__device__ __forceinline__ void relu_store_hs16(
        unsigned short* Hs, const float* __restrict__ bias,
        floatx4 acc[8], int wav, int lane) {
    int quad = lane >> 4, mrow = lane & 15;
    #pragma unroll
    for (int nt = 0; nt < 8; ++nt) {
        int colc = nt * 16 + mrow;
        float bcol = bias[colc];
        #pragma unroll
        for (int r = 0; r < 4; ++r) {
            int rowl = wav * 16 + quad * 4 + r;
            Hs[rowl * HS_STRIDE + colc] = f2bf(fmaxf(acc[nt][r] + bcol, 0.f));
        }
    }
}

// ---- aggregation phase (device fn): 64 nodes/block, 256 threads -----------
// Quarter-wave per node, 4 nodes sequential per quarter. R19's proven
// no-spill body: on-demand col loads, no cross-iteration register state.

__device__ __forceinline__ void agg_to_hs(
        const unsigned char* __restrict__ t8, const int* __restrict__ rowptr,
        const int* __restrict__ col, const float* __restrict__ dinv,
        const float* __restrict__ bias, unsigned short* Hs, int n) {
    int tid = threadIdx.x;
    int lane = tid & 63;
    int q16 = lane >> 4;            // quarter (node) within wave
    int lq  = lane & 15;            // edge slot within half-round
    int oct = (lane >> 3) & 1;      // which of 2 rows this lane helps load
    int l8  = lane & 7;             // 16B chunk within row
    int qrow0 = (tid >> 4) * 4;     // local row base for this quarter (0..60)
    const float4* b4 = (const float4*)bias;

    for (int it = 0; it < 4; ++it) {
        int rowl = qrow0 + it;
        int node = blockIdx.x * ROWS + rowl;
        if (node >= n) node = n - 1;    // dup work in tail, benign
        floatx2 acc[8];                 // cols 16*l8 .. +16
        #pragma unroll
        for (int i = 0; i < 8; ++i) acc[i] = (floatx2){0.f, 0.f};

        int beg = rowptr[node];
        int deg = rowptr[node + 1] - beg;
        for (int base = 0; base < deg; base += 32) {
            int m = deg - base;
            int jv0 = (lq < m)      ? col[beg + base + lq]      : n;   // n = zero row
            int jv1 = (lq + 16 < m) ? col[beg + base + 16 + lq] : n;
            uint4 v[16];
            #pragma unroll
            for (int q = 0; q < 8; ++q) {
                int j = __shfl(jv0, q16 * 16 + q * 2 + oct);
                v[q] = ((const uint4*)(t8 + (size_t)j * 128))[l8];
            }
            #pragma unroll
            for (int q = 0; q < 8; ++q) {
                int j = __shfl(jv1, q16 * 16 + q * 2 + oct);
                v[8 + q] = ((const uint4*)(t8 + (size_t)j * 128))[l8];
            }
            #pragma unroll
            for (int q = 0; q < 16; ++q) {
                acc[0] += __builtin_amdgcn_cvt_pk_f32_fp8(v[q].x, false);
                acc[1] += __builtin_amdgcn_cvt_pk_f32_fp8(v[q].x, true);
                acc[2] += __builtin_amdgcn_cvt_pk_f32_fp8(v[q].y, false);
                acc[3] += __builtin_amdgcn_cvt_pk_f32_fp8(v[q].y, true);
                acc[4] += __builtin_amdgcn_cvt_pk_f32_fp8(v[q].z, false);
                acc[5] += __builtin_amdgcn_cvt_pk_f32_fp8(v[q].z, true);
                acc[6] += __builtin_amdgcn_cvt_pk_f32_fp8(v[q].w, false);
                acc[7] += __builtin_amdgcn_cvt_pk_f32_fp8(v[q].w, true);
            }
        }
        #pragma unroll
        for (int i = 0; i < 8; ++i) {
            acc[i].x += __shfl_xor(acc[i].x, 8);
            acc[i].y += __shfl_xor(acc[i].y, 8);
        }
        uint4 s = ((const uint4*)(t8 + (size_t)node * 128))[l8];
        acc[0] += __builtin_amdgcn_cvt_pk_f32_fp8(s.x, false);
        acc[1] += __builtin_amdgcn_cvt_pk_f32_fp8(s.x, true);
        acc[2] += __builtin_amdgcn_cvt_pk_f32_fp8(s.y, false);
        acc[3] += __builtin_amdgcn_cvt_pk_f32_fp8(s.y, true);
        acc[4] += __builtin_amdgcn_cvt_pk_f32_fp8(s.z, false);
        acc[5] += __builtin_amdgcn_cvt_pk_f32_fp8(s.z, true);
        acc[6] += __builtin_amdgcn_cvt_pk_f32_fp8(s.w, false);
        acc[7] += __builtin_amdgcn_cvt_pk_f32_fp8(s.w, true);

        float di = dinv[node];
        float o[16];
        #pragma unroll
        for (int k = 0; k < 4; ++k) {
            float4 bb = b4[l8 * 4 + k];
            o[k*4+0] = fmaxf(di * acc[k*2].x   + bb.x, 0.f);
            o[k*4+1] = fmaxf(di * acc[k*2].y   + bb.y, 0.f);
            o[k*4+2] = fmaxf(di * acc[k*2+1].x + bb.z, 0.f);
            o[k*4+3] = fmaxf(di * acc[k*2+1].y + bb.w, 0.f);
        }
        if (oct == 0) {                 // write bf16 row chunk to LDS
            unsigned short* hp = Hs + rowl * HS_STRIDE + l8 * 16;
            uint2 w;
            w.x = pk_bf(o[0],  o[1]);  w.y = pk_bf(o[2],  o[3]);
            *(uint2*)(hp)      = w;
            w.x = pk_bf(o[4],  o[5]);  w.y = pk_bf(o[6],  o[7]);
            *(uint2*)(hp + 4)  = w;
            w.x = pk_bf(o[8],  o[9]);  w.y = pk_bf(o[10], o[11]);
            *(uint2*)(hp + 8)  = w;
            w.x = pk_bf(o[12], o[13]); w.y = pk_bf(o[14], o[15]);
            *(uint2*)(hp + 12) = w;
        }
    }
}

// ---- fused agg + encoder GEMM: t8_out = fp8( dinv * (agg(t8_in) @ W) ) ----
// 64 rows/block. One barrier between agg and GEMM (row ownership crosses
// waves); all 4 waves then run independent 16-row GEMM tiles.

__global__ __launch_bounds__(256, 3) void agg_gemm_kernel(
        const unsigned char* __restrict__ t8, const int* __restrict__ rowptr,
        const int* __restrict__ col, const float* __restrict__ dinv,
        const float* __restrict__ bias, const unsigned short* __restrict__ Wp,
        unsigned char* __restrict__ outp, int n) {
    __shared__ unsigned short Hs[ROWS * HS_STRIDE];
    agg_to_hs(t8, rowptr, col, dinv, bias, Hs, n);
    __syncthreads();

    int tid = threadIdx.x;
    int wav = tid >> 6, lane = tid & 63;
    int quad = lane >> 4, mrow = lane & 15;
    int row0 = blockIdx.x * ROWS + wav * 16;

    floatx4 acc[8];
    gemm_lds16(Hs, Wp, wav, lane, acc);

    int rbase = row0 + quad * 4;
    float dv[4];
    #pragma unroll
    for (int r = 0; r < 4; ++r)
        dv[r] = (rbase + r < n) ? dinv[rbase + r] : 0.f;
    #pragma unroll
    for (int nt = 0; nt < 8; ++nt) {
        int colc = nt * 16 + mrow;
        #pragma unroll
        for (int r = 0; r < 4; ++r) {
            int row = rbase + r;
            if (row < n)
                outp[(size_t)row * 128 + colc] = f2fp8(acc[nt][r] * dv[r]);
        }
    }
}

// ---- fused agg + decoder: agg -> GEMM(W_sd) -> 2x GEMM(W_md) -> proj+res --
// Stages 2/3 are wave-private (each wave reads/writes its own 16-row tile).

__global__ __launch_bounds__(256, 3) void agg_dec_kernel(
        const unsigned char* __restrict__ t8, const int* __restrict__ rowptr,
        const int* __restrict__ col, const float* __restrict__ dinv,
        const float* __restrict__ bias,
        const unsigned short* __restrict__ Wp_sd, const float* __restrict__ b_sd,
        const unsigned short* __restrict__ Wp_md, const float* __restrict__ b_md,
        const float* __restrict__ W_ed, const float* __restrict__ b_ed,
        const float* __restrict__ x, float* __restrict__ out, int n) {
    __shared__ unsigned short Hs[ROWS * HS_STRIDE];
    agg_to_hs(t8, rowptr, col, dinv, bias, Hs, n);
    __syncthreads();

    int tid = threadIdx.x;
    int wav = tid >> 6, lane = tid & 63;
    int quad = lane >> 4, mrow = lane & 15;
    int row0 = blockIdx.x * ROWS + wav * 16;

    floatx4 acc[8];
    // stage 1: h @ W_sd
    gemm_lds16(Hs, Wp_sd, wav, lane, acc);
    relu_store_hs16(Hs, b_sd, acc, wav, lane);
    // stage 2: @ W_md (16-row tile wave-private from here on)
    gemm_lds16(Hs, Wp_md, wav, lane, acc);
    relu_store_hs16(Hs, b_md, acc, wav, lane);
    // stage 3: @ W_md
    gemm_lds16(Hs, Wp_md, wav, lane, acc);

    // out-projection: relu(acc+b_md) @ W_ed + b_ed + x
    float wed[8][3];
    #pragma unroll
    for (int nt = 0; nt < 8; ++nt) {
        int c = nt * 16 + mrow;
        #pragma unroll
        for (int k = 0; k < 3; ++k) wed[nt][k] = W_ed[c * 3 + k];
    }
    #pragma unroll
    for (int r = 0; r < 4; ++r) {
        float s0 = 0.f, s1 = 0.f, s2 = 0.f;
        #pragma unroll
        for (int nt = 0; nt < 8; ++nt) {
            float v = fmaxf(acc[nt][r] + b_md[nt * 16 + mrow], 0.f);
            s0 += v * wed[nt][0]; s1 += v * wed[nt][1]; s2 += v * wed[nt][2];
        }
        #pragma unroll
        for (int off = 1; off < 16; off <<= 1) {
            s0 += __shfl_xor(s0, off);
            s1 += __shfl_xor(s1, off);
            s2 += __shfl_xor(s2, off);
        }
        if (mrow == 0) {
            int row = row0 + quad * 4 + r;
            if (row < n) {
                out[row * 3 + 0] = s0 + b_ed[0] + x[row * 3 + 0];
                out[row * 3 + 1] = s1 + b_ed[1] + x[row * 3 + 1];
                out[row * 3 + 2] = s2 + b_ed[2] + x[row * 3 + 2];
            }
        }
    }
}

// ---------------------------------------------------------------------------

extern "C" void kernel_launch(void* const* d_in, const int* in_sizes, int n_in,
                              void* d_out, int out_size, void* d_ws, size_t ws_size,
                              hipStream_t stream) {
    const float* x    = (const float*)d_in[0];
    const int*   ei   = (const int*)d_in[1];
    const float* W_s  = (const float*)d_in[2];
    const float* b_s  = (const float*)d_in[3];
    const float* W_m  = (const float*)d_in[4];
    const float* b_m  = (const float*)d_in[5];
    const float* W_e  = (const float*)d_in[6];
    const float* b_e  = (const float*)d_in[7];
    const float* W_sd = (const float*)d_in[8];
    const float* b_sd = (const float*)d_in[9];
    const float* W_md = (const float*)d_in[10];
    const float* b_md = (const float*)d_in[11];
    const float* W_ed = (const float*)d_in[12];
    const float* b_ed = (const float*)d_in[13];
    float* outp = (float*)d_out;

    const int N = in_sizes[0] / 3;
    const int E = in_sizes[1] / 2;
    const int* src = ei;
    const int* dst = ei + E;

    const int NB = (N + BKT - 1) / BKT;                  // 256-node buckets
    const int C  = (((E / NB) * 3 / 2) + 255) & ~255;    // segment cap, 1.5x mean

    char* p = (char*)d_ws;
    auto carve = [&](size_t bytes) {
        void* r = (void*)p;
        p += (bytes + 255) & ~(size_t)255;
        return r;
    };
    int*   rowptr = (int*)  carve((size_t)(N + 1) * 4);
    int*   col    = (int*)  carve((size_t)E * 4);
    float* dinv   = (float*)carve((size_t)N * 4);
    int*   gfill  = (int*)  carve((size_t)NB * 4);
    unsigned int* binbuf = (unsigned int*)carve((size_t)NB * C * 4);
    unsigned short* Wp_m  = (unsigned short*)carve(16384 * 2);
    unsigned short* Wp_e  = (unsigned short*)carve(16384 * 2);
    unsigned short* Wp_sd = (unsigned short*)carve(16384 * 2);
    unsigned short* Wp_md = (unsigned short*)carve(16384 * 2);
    unsigned char*  T8a = (unsigned char*) carve((size_t)(N + 1) * 128);   // +1 zero row
    unsigned char*  T8b = (unsigned char*) carve((size_t)(N + 1) * 128);   // ping-pong
    (void)ws_size;

    const int gBin = (E + BIN_CH - 1) / BIN_CH;
    const int gRow64 = (N + ROWS - 1) / ROWS;

    // weight packs + buffer init (no deps)
    pack_kernel<<<32, 256, 0, stream>>>(W_m, W_e, W_sd, W_md, Wp_m, Wp_e, Wp_sd, Wp_md,
                                        gfill, T8a + (size_t)N * 128,
                                        T8b + (size_t)N * 128, NB);

    // graph build
    bin_kernel<<<gBin, 512, 0, stream>>>(src, dst, gfill, binbuf, NB, C, E);
    build_kernel<<<NB, 256, 0, stream>>>(binbuf, gfill, rowptr, dinv, col, NB, C, N, E);

    // encoder: t' in fp8; agg+GEMM fused, T8 ping-pong kills in-place race
    in_gemm_kernel<<<(N * 64 + 255) / 256, 256, 0, stream>>>(x, W_s, dinv, T8a, N);
    agg_gemm_kernel<<<gRow64, 256, 0, stream>>>(T8a, rowptr, col, dinv, b_s, Wp_m, T8b, N);
    agg_gemm_kernel<<<gRow64, 256, 0, stream>>>(T8b, rowptr, col, dinv, b_m, Wp_m, T8a, N);
    agg_gemm_kernel<<<gRow64, 256, 0, stream>>>(T8a, rowptr, col, dinv, b_m, Wp_e, T8b, N);

    // fused 4th agg + decoder
    agg_dec_kernel<<<gRow64, 256, 0, stream>>>(T8b, rowptr, col, dinv, b_e,
                                               Wp_sd, b_sd, Wp_md, b_md,
                                               W_ed, b_ed, x, outp, N);
}

// Round 8
// 362.304 us; speedup vs baseline: 1.0831x; 1.0494x over previous
//
#include <hip/hip_runtime.h>

// ---------------------------------------------------------------------------
// GCN encoder (4 conv layers, shared CSR graph) + 3-layer MLP decoder.
// Round 24: R23's N-split decoder failed the determinism tripwire (cross-wave
// interleaved Hs writes — every passing variant kept Hs writes wave-private).
// Revert to proven components only: passes 1-3 = R19 fused agg_gemm (best
// passing, 372.9us); pass 4 = split: baseline agg_kernel (6250 blocks, global
// bf16 A) + R18 decoder_kernel (global weights, zero barriers, wave-private
// Hs). R19 profile: agg_dec=93us; split pair covers it in ~60us.
// ---------------------------------------------------------------------------

typedef __attribute__((ext_vector_type(8))) short short8;
typedef __attribute__((ext_vector_type(4))) float floatx4;
typedef __attribute__((ext_vector_type(2))) float floatx2;

#define BIN_CH 8192          // edges per bin block
#define NBMAX 512            // max buckets supported
#define BKT 256              // nodes per bucket
#define HS_STRIDE 68         // LDS row stride in ushorts (136 B)

__device__ __forceinline__ unsigned short f2bf(float f) {
    unsigned int u = __float_as_uint(f);
    u += 0x7fffu + ((u >> 16) & 1u);          // round-to-nearest-even
    return (unsigned short)(u >> 16);
}
__device__ __forceinline__ unsigned int pk_bf(float a, float b) {
    return (unsigned int)f2bf(a) | ((unsigned int)f2bf(b) << 16);
}
__device__ __forceinline__ unsigned char f2fp8(float f) {
    return (unsigned char)(__builtin_amdgcn_cvt_pk_fp8_f32(f, f, 0, false) & 0xFF);
}
__device__ __forceinline__ short8 ld_frag(const unsigned short* p) {
    uint2 a = *(const uint2*)p;
    uint2 b = *(const uint2*)(p + 4);
    int4 v = make_int4((int)a.x, (int)a.y, (int)b.x, (int)b.y);
    return __builtin_bit_cast(short8, v);
}

// ---- weight pre-pack + buffer init (runs first) ---------------------------

__global__ void pack_kernel(const float* __restrict__ W0, const float* __restrict__ W1,
                            const float* __restrict__ W2, const float* __restrict__ W3,
                            unsigned short* __restrict__ P0, unsigned short* __restrict__ P1,
                            unsigned short* __restrict__ P2, unsigned short* __restrict__ P3,
                            int* __restrict__ gfill, unsigned char* __restrict__ t8zrowA,
                            unsigned char* __restrict__ t8zrowB, int NB) {
    if (blockIdx.x == 0) {                       // fold the memsets
        for (int i = threadIdx.x; i < NB; i += 256) gfill[i] = 0;
        if (threadIdx.x < 32) {
            ((unsigned int*)t8zrowA)[threadIdx.x] = 0;
            ((unsigned int*)t8zrowB)[threadIdx.x] = 0;
        }
    }
    int which = blockIdx.x >> 3;
    const float* W = which == 0 ? W0 : which == 1 ? W1 : which == 2 ? W2 : W3;
    unsigned short* P = which == 0 ? P0 : which == 1 ? P1 : which == 2 ? P2 : P3;
    int f = (blockIdx.x & 7) * 256 + threadIdx.x;
    int lane = f & 63, nt = (f >> 6) & 7, kc = f >> 9;
    int kbase = kc * 32 + (lane >> 4) * 8;
    int ncol = nt * 16 + (lane & 15);
    short8 frag;
    #pragma unroll
    for (int j = 0; j < 8; ++j)
        frag[j] = (short)f2bf(W[(size_t)(kbase + j) * 128 + ncol]);
    *((short8*)(P + (size_t)f * 8)) = frag;
}

// ---- graph build ----------------------------------------------------------
// entry = (d & 255) << 17 | src   (src < 2^17)

__global__ __launch_bounds__(512) void bin_kernel(
        const int* __restrict__ src, const int* __restrict__ dst,
        int* __restrict__ gfill, unsigned int* __restrict__ binbuf,
        int NB, int C, int E) {
    __shared__ int h4[4][NBMAX];     // per-group counts -> cursors
    __shared__ int start[NBMAX];
    __shared__ int tot[NBMAX];
    __shared__ int dstoff[NBMAX];
    int tid = threadIdx.x;
    int grp = tid >> 7;
    int e0 = blockIdx.x * BIN_CH;
    for (int i = tid; i < 4 * NBMAX; i += 512) ((int*)h4)[i] = 0;
    __syncthreads();
    for (int i = tid; i < BIN_CH; i += 512) {
        int e = e0 + i;
        if (e < E) atomicAdd(&h4[grp][dst[e] >> 8], 1);
    }
    __syncthreads();
    if (tid < 64) {        // wave 0: totals, exclusive scan, per-group bases
        int carry = 0;
        for (int base = 0; base < NB; base += 64) {
            int idx = base + tid;
            int c0 = 0, c1 = 0, c2 = 0, c3 = 0, v = 0;
            if (idx < NB) {
                c0 = h4[0][idx]; c1 = h4[1][idx];
                c2 = h4[2][idx]; c3 = h4[3][idx];
                v = c0 + c1 + c2 + c3;
            }
            int s = v;
            #pragma unroll
            for (int off = 1; off < 64; off <<= 1) {
                int u = __shfl_up(s, off);
                if (tid >= off) s += u;
            }
            if (idx < NB) {
                int ex = carry + s - v;
                start[idx] = ex;
                tot[idx] = v;
                h4[0][idx] = ex;
                h4[1][idx] = ex + c0;
                h4[2][idx] = ex + c0 + c1;
                h4[3][idx] = ex + c0 + c1 + c2;
            }
            carry += __shfl(s, 63);
        }
    }
    __syncthreads();
    for (int i = tid; i < NB; i += 512) {   // reserve global runs
        int cnt = tot[i];
        int g = cnt ? atomicAdd(&gfill[i], cnt) : 0;
        dstoff[i] = g - start[i];
    }
    __syncthreads();
    for (int i = tid; i < BIN_CH; i += 512) {
        int e = e0 + i;
        if (e >= E) continue;
        int d = dst[e];
        int b = d >> 8;
        int slot = atomicAdd(&h4[grp][b], 1);         // block-local rank
        int gidx = b * C + dstoff[b] + slot;
        if (gidx < (b + 1) * C)
            binbuf[gidx] = (unsigned int)src[e] | ((unsigned int)(d & 255) << 17);
    }
}

// one block per bucket: split hist(4x256) -> scan -> rowptr/dinv -> place.
// Bucket base computed in-kernel (wave 1 sums gfill[0..b)).
__global__ __launch_bounds__(256) void build_kernel(
        const unsigned int* __restrict__ binbuf, const int* __restrict__ gfill,
        int* __restrict__ rowptr, float* __restrict__ dinv, int* __restrict__ col,
        int NB, int C, int N, int E) {
    __shared__ int h4[4][BKT];       // per-group counts -> cursors
    __shared__ int hs[BKT];          // exclusive scan of totals
    __shared__ int tot[BKT];
    __shared__ int bbase_s;
    int b = blockIdx.x, tid = threadIdx.x;
    int grp = tid >> 6;
    int cnt = gfill[b];
    const unsigned int* p = binbuf + (size_t)b * C;
    for (int i = tid; i < 4 * BKT; i += 256) ((int*)h4)[i] = 0;
    __syncthreads();
    if (tid >= 64 && tid < 128) {          // wave 1: base = sum gfill[0..b)
        int l = tid - 64;
        int s = 0;
        for (int i = l; i < b; i += 64) s += gfill[i];
        #pragma unroll
        for (int off = 32; off > 0; off >>= 1) s += __shfl_down(s, off);
        if (l == 0) bbase_s = s;
    }
    for (int i = tid; i < cnt; i += 256) atomicAdd(&h4[grp][p[i] >> 17], 1);
    __syncthreads();
    if (tid < 64) {        // wave 0: totals, scan, per-group cursor bases
        int carry = 0;
        for (int base = 0; base < BKT; base += 64) {
            int idx = base + tid;
            int c0 = h4[0][idx], c1 = h4[1][idx], c2 = h4[2][idx], c3 = h4[3][idx];
            int v = c0 + c1 + c2 + c3;
            int s = v;
            #pragma unroll
            for (int off = 1; off < 64; off <<= 1) {
                int u = __shfl_up(s, off);
                if (tid >= off) s += u;
            }
            int ex = carry + s - v;
            hs[idx] = ex;
            tot[idx] = v;
            h4[0][idx] = ex;
            h4[1][idx] = ex + c0;
            h4[2][idx] = ex + c0 + c1;
            h4[3][idx] = ex + c0 + c1 + c2;
            carry += __shfl(s, 63);
        }
    }
    __syncthreads();
    int base = bbase_s;
    if (tid < BKT) {
        int node = b * BKT + tid;
        if (node < N) {
            rowptr[node] = base + hs[tid];
            dinv[node] = 1.0f / sqrtf((float)(tot[tid] + 1));
        }
    }
    if (b == 0 && tid == 0) rowptr[N] = E;
    __syncthreads();
    for (int i = tid; i < cnt; i += 256) {  // place via per-group cursors
        unsigned int u = p[i];
        int local = u >> 17;
        int pos = atomicAdd(&h4[grp][local], 1);
        col[base + pos] = (int)(u & 0x1FFFFu);
    }
}

// ---- input layer: t' = fp8( dinv_i * (x @ W_s) ) --------------------------

__global__ void in_gemm_kernel(const float* __restrict__ x, const float* __restrict__ W,
                               const float* __restrict__ dinv,
                               unsigned char* __restrict__ t8, int n) {
    int g = blockIdx.x * 256 + threadIdx.x;
    int i = g >> 6, c2 = g & 63;
    if (i >= n) return;
    float x0 = x[i * 3], x1 = x[i * 3 + 1], x2 = x[i * 3 + 2];
    float d = dinv[i];
    int c = c2 * 2;
    float v0 = d * (x0 * W[c]     + x1 * W[128 + c]     + x2 * W[256 + c]);
    float v1 = d * (x0 * W[c + 1] + x1 * W[128 + c + 1] + x2 * W[256 + c + 1]);
    unsigned int pk = __builtin_amdgcn_cvt_pk_fp8_f32(v0, v1, 0, false);
    ((unsigned short*)t8)[(size_t)i * 64 + c2] = (unsigned short)(pk & 0xFFFF);
}

// ---- split aggregation (pass 4): out_i = relu(d_i*(t'_i + sum t'_j) + b) --
// Baseline-proven: 16 nodes/block, 1 node per quarter-wave, bf16 out global.

__global__ __launch_bounds__(256) void agg_kernel(
        const unsigned char* __restrict__ t8, const int* __restrict__ rowptr,
        const int* __restrict__ col, const float* __restrict__ dinv,
        const float* __restrict__ bias, unsigned short* __restrict__ out, int n) {
    int node = blockIdx.x * 16 + (threadIdx.x >> 4);
    int lane = threadIdx.x & 63;
    int q16 = lane >> 4;            // quarter (node) within wave
    int lq  = lane & 15;            // edge slot within half-round
    int oct = (lane >> 3) & 1;      // which of 2 rows this lane helps load
    int l8  = lane & 7;             // 16B chunk within row
    if (node >= n) node = n - 1;    // dup work in tail, benign
    floatx2 acc[8];                 // cols 16*l8 .. +16
    #pragma unroll
    for (int i = 0; i < 8; ++i) acc[i] = (floatx2){0.f, 0.f};

    int beg = rowptr[node];
    int deg = rowptr[node + 1] - beg;
    for (int base = 0; base < deg; base += 32) {
        int m = deg - base;
        int jv0 = (lq < m)      ? col[beg + base + lq]      : n;   // n = zero row
        int jv1 = (lq + 16 < m) ? col[beg + base + 16 + lq] : n;
        uint4 v[16];
        #pragma unroll
        for (int q = 0; q < 8; ++q) {
            int j = __shfl(jv0, q16 * 16 + q * 2 + oct);
            v[q] = ((const uint4*)(t8 + (size_t)j * 128))[l8];
        }
        #pragma unroll
        for (int q = 0; q < 8; ++q) {
            int j = __shfl(jv1, q16 * 16 + q * 2 + oct);
            v[8 + q] = ((const uint4*)(t8 + (size_t)j * 128))[l8];
        }
        #pragma unroll
        for (int q = 0; q < 16; ++q) {
            acc[0] += __builtin_amdgcn_cvt_pk_f32_fp8(v[q].x, false);
            acc[1] += __builtin_amdgcn_cvt_pk_f32_fp8(v[q].x, true);
            acc[2] += __builtin_amdgcn_cvt_pk_f32_fp8(v[q].y, false);
            acc[3] += __builtin_amdgcn_cvt_pk_f32_fp8(v[q].y, true);
            acc[4] += __builtin_amdgcn_cvt_pk_f32_fp8(v[q].z, false);
            acc[5] += __builtin_amdgcn_cvt_pk_f32_fp8(v[q].z, true);
            acc[6] += __builtin_amdgcn_cvt_pk_f32_fp8(v[q].w, false);
            acc[7] += __builtin_amdgcn_cvt_pk_f32_fp8(v[q].w, true);
        }
    }
    #pragma unroll
    for (int i = 0; i < 8; ++i) {
        acc[i].x += __shfl_xor(acc[i].x, 8);
        acc[i].y += __shfl_xor(acc[i].y, 8);
    }
    uint4 s = ((const uint4*)(t8 + (size_t)node * 128))[l8];
    acc[0] += __builtin_amdgcn_cvt_pk_f32_fp8(s.x, false);
    acc[1] += __builtin_amdgcn_cvt_pk_f32_fp8(s.x, true);
    acc[2] += __builtin_amdgcn_cvt_pk_f32_fp8(s.y, false);
    acc[3] += __builtin_amdgcn_cvt_pk_f32_fp8(s.y, true);
    acc[4] += __builtin_amdgcn_cvt_pk_f32_fp8(s.z, false);
    acc[5] += __builtin_amdgcn_cvt_pk_f32_fp8(s.z, true);
    acc[6] += __builtin_amdgcn_cvt_pk_f32_fp8(s.w, false);
    acc[7] += __builtin_amdgcn_cvt_pk_f32_fp8(s.w, true);

    float di = dinv[node];
    const float4* b4 = (const float4*)bias;     // cols 16*l8 .. +16
    float o[16];
    #pragma unroll
    for (int k = 0; k < 4; ++k) {
        float4 bb = b4[l8 * 4 + k];
        o[k*4+0] = fmaxf(di * acc[k*2].x   + bb.x, 0.f);
        o[k*4+1] = fmaxf(di * acc[k*2].y   + bb.y, 0.f);
        o[k*4+2] = fmaxf(di * acc[k*2+1].x + bb.z, 0.f);
        o[k*4+3] = fmaxf(di * acc[k*2+1].y + bb.w, 0.f);
    }
    if (oct == 0) {
        uint4 w0, w1;
        w0.x = pk_bf(o[0],  o[1]);  w0.y = pk_bf(o[2],  o[3]);
        w0.z = pk_bf(o[4],  o[5]);  w0.w = pk_bf(o[6],  o[7]);
        w1.x = pk_bf(o[8],  o[9]);  w1.y = pk_bf(o[10], o[11]);
        w1.z = pk_bf(o[12], o[13]); w1.w = pk_bf(o[14], o[15]);
        ((uint4*)(out + (size_t)node * 128))[l8 * 2]     = w0;
        ((uint4*)(out + (size_t)node * 128))[l8 * 2 + 1] = w1;
    }
}

// ---- shared GEMM pieces (32-row wave tiles, M-split — wave-private) -------
// Ws points at global packed weights (L1/L2-hot, shared by all blocks).

__device__ __forceinline__ void gemm_regs(const short8 af[2][4], const unsigned short* Ws,
                                          int lane, floatx4 acc[2][8]) {
    #pragma unroll
    for (int t = 0; t < 2; ++t)
        #pragma unroll
        for (int nt = 0; nt < 8; ++nt) acc[t][nt] = (floatx4){0.f, 0.f, 0.f, 0.f};
    #pragma unroll
    for (int kc = 0; kc < 4; ++kc) {
        #pragma unroll
        for (int nt = 0; nt < 8; ++nt) {
            short8 bf = *((const short8*)(Ws + ((kc * 8 + nt) * 64 + lane) * 8));
            acc[0][nt] = __builtin_amdgcn_mfma_f32_16x16x32_bf16(af[0][kc], bf, acc[0][nt], 0, 0, 0);
            acc[1][nt] = __builtin_amdgcn_mfma_f32_16x16x32_bf16(af[1][kc], bf, acc[1][nt], 0, 0, 0);
        }
    }
}

__device__ __forceinline__ void gemm_lds(const unsigned short* Hs, const unsigned short* Ws,
                                         int wav, int lane, floatx4 acc[2][8]) {
    int quad = lane >> 4, mrow = lane & 15;
    short8 af[2][4];
    #pragma unroll
    for (int t = 0; t < 2; ++t)
        #pragma unroll
        for (int kc = 0; kc < 4; ++kc)
            af[t][kc] = ld_frag(Hs + (wav * 32 + t * 16 + mrow) * HS_STRIDE + (kc * 4 + quad) * 8);
    gemm_regs(af, Ws, lane, acc);
}

__device__ __forceinline__ void relu_store_hs(
        unsigned short* Hs, const float* __restrict__ bias,
        floatx4 acc[2][8], int wav, int lane) {
    int quad = lane >> 4, mrow = lane & 15;
    #pragma unroll
    for (int t = 0; t < 2; ++t) {
        #pragma unroll
        for (int nt = 0; nt < 8; ++nt) {
            int colc = nt * 16 + mrow;
            float bcol = bias[colc];
            #pragma unroll
            for (int r = 0; r < 4; ++r) {
                int rowl = wav * 32 + t * 16 + quad * 4 + r;
                Hs[rowl * HS_STRIDE + colc] = f2bf(fmaxf(acc[t][nt][r] + bcol, 0.f));
            }
        }
    }
}

// ---- fused aggregation phase (R19): 128 nodes/block -> relu'd bf16 Hs -----
// Quarter-wave per node, 8 nodes sequential per quarter; wave-private rows.

__device__ __forceinline__ void agg_to_hs(
        const unsigned char* __restrict__ t8, const int* __restrict__ rowptr,
        const int* __restrict__ col, const float* __restrict__ dinv,
        const float* __restrict__ bias, unsigned short* Hs, int n) {
    int tid = threadIdx.x;
    int lane = tid & 63;
    int q16 = lane >> 4;            // quarter (node) within wave
    int lq  = lane & 15;            // edge slot within half-round
    int oct = (lane >> 3) & 1;      // which of 2 rows this lane helps load
    int l8  = lane & 7;             // 16B chunk within row
    int qrow0 = (tid >> 4) * 8;     // local row base for this quarter
    const float4* b4 = (const float4*)bias;

    for (int it = 0; it < 8; ++it) {
        int rowl = qrow0 + it;
        int node = blockIdx.x * 128 + rowl;
        if (node >= n) node = n - 1;    // dup work in tail, benign
        floatx2 acc[8];                 // cols 16*l8 .. +16
        #pragma unroll
        for (int i = 0; i < 8; ++i) acc[i] = (floatx2){0.f, 0.f};

        int beg = rowptr[node];
        int deg = rowptr[node + 1] - beg;
        for (int base = 0; base < deg; base += 32) {
            int m = deg - base;
            int jv0 = (lq < m)      ? col[beg + base + lq]      : n;   // n = zero row
            int jv1 = (lq + 16 < m) ? col[beg + base + 16 + lq] : n;
            uint4 v[16];
            #pragma unroll
            for (int q = 0; q < 8; ++q) {
                int j = __shfl(jv0, q16 * 16 + q * 2 + oct);
                v[q] = ((const uint4*)(t8 + (size_t)j * 128))[l8];
            }
            #pragma unroll
            for (int q = 0; q < 8; ++q) {
                int j = __shfl(jv1, q16 * 16 + q * 2 + oct);
                v[8 + q] = ((const uint4*)(t8 + (size_t)j * 128))[l8];
            }
            #pragma unroll
            for (int q = 0; q < 16; ++q) {
                acc[0] += __builtin_amdgcn_cvt_pk_f32_fp8(v[q].x, false);
                acc[1] += __builtin_amdgcn_cvt_pk_f32_fp8(v[q].x, true);
                acc[2] += __builtin_amdgcn_cvt_pk_f32_fp8(v[q].y, false);
                acc[3] += __builtin_amdgcn_cvt_pk_f32_fp8(v[q].y, true);
                acc[4] += __builtin_amdgcn_cvt_pk_f32_fp8(v[q].z, false);
                acc[5] += __builtin_amdgcn_cvt_pk_f32_fp8(v[q].z, true);
                acc[6] += __builtin_amdgcn_cvt_pk_f32_fp8(v[q].w, false);
                acc[7] += __builtin_amdgcn_cvt_pk_f32_fp8(v[q].w, true);
            }
        }
        #pragma unroll
        for (int i = 0; i < 8; ++i) {
            acc[i].x += __shfl_xor(acc[i].x, 8);
            acc[i].y += __shfl_xor(acc[i].y, 8);
        }
        uint4 s = ((const uint4*)(t8 + (size_t)node * 128))[l8];
        acc[0] += __builtin_amdgcn_cvt_pk_f32_fp8(s.x, false);
        acc[1] += __builtin_amdgcn_cvt_pk_f32_fp8(s.x, true);
        acc[2] += __builtin_amdgcn_cvt_pk_f32_fp8(s.y, false);
        acc[3] += __builtin_amdgcn_cvt_pk_f32_fp8(s.y, true);
        acc[4] += __builtin_amdgcn_cvt_pk_f32_fp8(s.z, false);
        acc[5] += __builtin_amdgcn_cvt_pk_f32_fp8(s.z, true);
        acc[6] += __builtin_amdgcn_cvt_pk_f32_fp8(s.w, false);
        acc[7] += __builtin_amdgcn_cvt_pk_f32_fp8(s.w, true);

        float di = dinv[node];
        float o[16];
        #pragma unroll
        for (int k = 0; k < 4; ++k) {
            float4 bb = b4[l8 * 4 + k];
            o[k*4+0] = fmaxf(di * acc[k*2].x   + bb.x, 0.f);
            o[k*4+1] = fmaxf(di * acc[k*2].y   + bb.y, 0.f);
            o[k*4+2] = fmaxf(di * acc[k*2+1].x + bb.z, 0.f);
            o[k*4+3] = fmaxf(di * acc[k*2+1].y + bb.w, 0.f);
        }
        if (oct == 0) {                 // write bf16 row chunk to LDS
            unsigned short* hp = Hs + rowl * HS_STRIDE + l8 * 16;
            uint2 w;
            w.x = pk_bf(o[0],  o[1]);  w.y = pk_bf(o[2],  o[3]);
            *(uint2*)(hp)      = w;
            w.x = pk_bf(o[4],  o[5]);  w.y = pk_bf(o[6],  o[7]);
            *(uint2*)(hp + 4)  = w;
            w.x = pk_bf(o[8],  o[9]);  w.y = pk_bf(o[10], o[11]);
            *(uint2*)(hp + 8)  = w;
            w.x = pk_bf(o[12], o[13]); w.y = pk_bf(o[14], o[15]);
            *(uint2*)(hp + 12) = w;
        }
    }
}

// ---- fused agg + encoder GEMM (R19): t8_out = fp8(dinv*(agg(t8_in)@W)) ----
// Wave-private Hs rows -> no barrier anywhere.

__global__ __launch_bounds__(256, 3) void agg_gemm_kernel(
        const unsigned char* __restrict__ t8, const int* __restrict__ rowptr,
        const int* __restrict__ col, const float* __restrict__ dinv,
        const float* __restrict__ bias, const unsigned short* __restrict__ Wp,
        unsigned char* __restrict__ outp, int n) {
    __shared__ unsigned short Hs[128 * HS_STRIDE];
    agg_to_hs(t8, rowptr, col, dinv, bias, Hs, n);

    int tid = threadIdx.x;
    int wav = tid >> 6, lane = tid & 63;
    int quad = lane >> 4, mrow = lane & 15;
    int row0 = blockIdx.x * 128 + wav * 32;

    floatx4 acc[2][8];
    gemm_lds(Hs, Wp, wav, lane, acc);

    #pragma unroll
    for (int t = 0; t < 2; ++t) {
        int rbase = row0 + t * 16 + quad * 4;
        float dv[4];
        #pragma unroll
        for (int r = 0; r < 4; ++r)
            dv[r] = (rbase + r < n) ? dinv[rbase + r] : 0.f;
        #pragma unroll
        for (int nt = 0; nt < 8; ++nt) {
            int colc = nt * 16 + mrow;
            #pragma unroll
            for (int r = 0; r < 4; ++r) {
                int row = rbase + r;
                if (row < n)
                    outp[(size_t)row * 128 + colc] = f2fp8(acc[t][nt][r] * dv[r]);
            }
        }
    }
}

// ---- decoder (R18): GEMM(W_sd) -> GEMM(W_md) -> GEMM(W_md)+proj+residual --
// Wave-independent: weights from global, Hs rows wave-private, zero barriers.

__global__ __launch_bounds__(256, 4) void decoder_kernel(
        const unsigned short* __restrict__ A,
        const unsigned short* __restrict__ Wp_sd, const float* __restrict__ b_sd,
        const unsigned short* __restrict__ Wp_md, const float* __restrict__ b_md,
        const float* __restrict__ W_ed, const float* __restrict__ b_ed,
        const float* __restrict__ x, float* __restrict__ out, int n) {
    __shared__ unsigned short Hs[128 * HS_STRIDE];
    int tid = threadIdx.x;
    int wav = tid >> 6, lane = tid & 63;
    int quad = lane >> 4, mrow = lane & 15;
    int row0 = blockIdx.x * 128 + wav * 32;

    short8 af[2][4];
    #pragma unroll
    for (int t = 0; t < 2; ++t) {
        int arow = row0 + t * 16 + mrow; if (arow >= n) arow = n - 1;
        const unsigned short* abase = A + (size_t)arow * 128 + quad * 8;
        #pragma unroll
        for (int kc = 0; kc < 4; ++kc)
            af[t][kc] = *((const short8*)(abase + kc * 32));
    }

    floatx4 acc[2][8];
    // stage 1: h @ W_sd
    gemm_regs(af, Wp_sd, lane, acc);
    relu_store_hs(Hs, b_sd, acc, wav, lane);
    // stage 2: @ W_md (Hs rows are wave-private -> no barrier anywhere)
    gemm_lds(Hs, Wp_md, wav, lane, acc);
    relu_store_hs(Hs, b_md, acc, wav, lane);
    // stage 3: @ W_md
    gemm_lds(Hs, Wp_md, wav, lane, acc);

    // out-projection: relu(acc+b_md) @ W_ed + b_ed + x
    float wed[8][3];
    #pragma unroll
    for (int nt = 0; nt < 8; ++nt) {
        int c = nt * 16 + mrow;
        #pragma unroll
        for (int k = 0; k < 3; ++k) wed[nt][k] = W_ed[c * 3 + k];
    }
    #pragma unroll
    for (int t = 0; t < 2; ++t) {
        #pragma unroll
        for (int r = 0; r < 4; ++r) {
            float s0 = 0.f, s1 = 0.f, s2 = 0.f;
            #pragma unroll
            for (int nt = 0; nt < 8; ++nt) {
                float v = fmaxf(acc[t][nt][r] + b_md[nt * 16 + mrow], 0.f);
                s0 += v * wed[nt][0]; s1 += v * wed[nt][1]; s2 += v * wed[nt][2];
            }
            #pragma unroll
            for (int off = 1; off < 16; off <<= 1) {
                s0 += __shfl_xor(s0, off);
                s1 += __shfl_xor(s1, off);
                s2 += __shfl_xor(s2, off);
            }
            if (mrow == 0) {
                int row = row0 + t * 16 + quad * 4 + r;
                if (row < n) {
                    out[row * 3 + 0] = s0 + b_ed[0] + x[row * 3 + 0];
                    out[row * 3 + 1] = s1 + b_ed[1] + x[row * 3 + 1];
                    out[row * 3 + 2] = s2 + b_ed[2] + x[row * 3 + 2];
                }
            }
        }
    }
}

// ---------------------------------------------------------------------------

extern "C" void kernel_launch(void* const* d_in, const int* in_sizes, int n_in,
                              void* d_out, int out_size, void* d_ws, size_t ws_size,
                              hipStream_t stream) {
    const float* x    = (const float*)d_in[0];
    const int*   ei   = (const int*)d_in[1];
    const float* W_s  = (const float*)d_in[2];
    const float* b_s  = (const float*)d_in[3];
    const float* W_m  = (const float*)d_in[4];
    const float* b_m  = (const float*)d_in[5];
    const float* W_e  = (const float*)d_in[6];
    const float* b_e  = (const float*)d_in[7];
    const float* W_sd = (const float*)d_in[8];
    const float* b_sd = (const float*)d_in[9];
    const float* W_md = (const float*)d_in[10];
    const float* b_md = (const float*)d_in[11];
    const float* W_ed = (const float*)d_in[12];
    const float* b_ed = (const float*)d_in[13];
    float* outp = (float*)d_out;

    const int N = in_sizes[0] / 3;
    const int E = in_sizes[1] / 2;
    const int* src = ei;
    const int* dst = ei + E;

    const int NB = (N + BKT - 1) / BKT;                  // 256-node buckets
    const int C  = (((E / NB) * 3 / 2) + 255) & ~255;    // segment cap, 1.5x mean

    char* p = (char*)d_ws;
    auto carve = [&](size_t bytes) {
        void* r = (void*)p;
        p += (bytes + 255) & ~(size_t)255;
        return r;
    };
    int*   rowptr = (int*)  carve((size_t)(N + 1) * 4);
    int*   col    = (int*)  carve((size_t)E * 4);
    float* dinv   = (float*)carve((size_t)N * 4);
    int*   gfill  = (int*)  carve((size_t)NB * 4);
    unsigned int* binbuf = (unsigned int*)carve((size_t)NB * C * 4);
    unsigned short* Wp_m  = (unsigned short*)carve(16384 * 2);
    unsigned short* Wp_e  = (unsigned short*)carve(16384 * 2);
    unsigned short* Wp_sd = (unsigned short*)carve(16384 * 2);
    unsigned short* Wp_md = (unsigned short*)carve(16384 * 2);
    unsigned char*  T8a = (unsigned char*) carve((size_t)(N + 1) * 128);   // +1 zero row
    unsigned char*  T8b = (unsigned char*) carve((size_t)(N + 1) * 128);   // ping-pong
    unsigned short* A   = (unsigned short*)carve((size_t)N * 128 * 2);     // bf16 enc out
    (void)ws_size;

    const int gBin = (E + BIN_CH - 1) / BIN_CH;
    const int gRow128 = (N + 127) / 128;
    const int gNode16 = (N + 15) / 16;

    // weight packs + buffer init (no deps)
    pack_kernel<<<32, 256, 0, stream>>>(W_m, W_e, W_sd, W_md, Wp_m, Wp_e, Wp_sd, Wp_md,
                                        gfill, T8a + (size_t)N * 128,
                                        T8b + (size_t)N * 128, NB);

    // graph build
    bin_kernel<<<gBin, 512, 0, stream>>>(src, dst, gfill, binbuf, NB, C, E);
    build_kernel<<<NB, 256, 0, stream>>>(binbuf, gfill, rowptr, dinv, col, NB, C, N, E);

    // encoder passes 1-3: fused agg+GEMM (R19), T8 ping-pong
    in_gemm_kernel<<<(N * 64 + 255) / 256, 256, 0, stream>>>(x, W_s, dinv, T8a, N);
    agg_gemm_kernel<<<gRow128, 256, 0, stream>>>(T8a, rowptr, col, dinv, b_s, Wp_m, T8b, N);
    agg_gemm_kernel<<<gRow128, 256, 0, stream>>>(T8b, rowptr, col, dinv, b_m, Wp_m, T8a, N);
    agg_gemm_kernel<<<gRow128, 256, 0, stream>>>(T8a, rowptr, col, dinv, b_m, Wp_e, T8b, N);

    // pass 4: split high-TLP agg -> global bf16 A, then barrier-free decoder
    agg_kernel<<<gNode16, 256, 0, stream>>>(T8b, rowptr, col, dinv, b_e, A, N);
    decoder_kernel<<<gRow128, 256, 0, stream>>>(A, Wp_sd, b_sd, Wp_md, b_md,
                                                W_ed, b_ed, x, outp, N);
}

// Round 9
// 359.298 us; speedup vs baseline: 1.0922x; 1.0084x over previous
//
#include <hip/hip_runtime.h>

// ---------------------------------------------------------------------------
// GCN encoder (4 conv layers, shared CSR graph) + 3-layer MLP decoder.
// Round 25: single change vs R24 (362.3us best): agg_gemm switches to the
// R22-proven ROWS=64 geometry (grid 1563, occupancy cap 12.2->24.4 waves/CU,
// depth-4 agg, one barrier, wave-private 16-row GEMM tiles). R24 counters:
// agg_gemm 55.3us, occ 24% grid-capped, VGPR 64 clean, FETCH 84MB@1.5TB/s
// (fabric headroom exists -> TLP-bound). Cross-round inference: R22's
// ROWS=64 agg_gemm ~= 49-50us. Pass 4 split (agg_kernel + decoder_kernel)
// and everything else byte-identical to R24.
// ---------------------------------------------------------------------------

typedef __attribute__((ext_vector_type(8))) short short8;
typedef __attribute__((ext_vector_type(4))) float floatx4;
typedef __attribute__((ext_vector_type(2))) float floatx2;

#define BIN_CH 8192          // edges per bin block
#define NBMAX 512            // max buckets supported
#define BKT 256              // nodes per bucket
#define HS_STRIDE 68         // LDS row stride in ushorts (136 B)
#define AG_ROWS 64           // rows per fused agg_gemm block

__device__ __forceinline__ unsigned short f2bf(float f) {
    unsigned int u = __float_as_uint(f);
    u += 0x7fffu + ((u >> 16) & 1u);          // round-to-nearest-even
    return (unsigned short)(u >> 16);
}
__device__ __forceinline__ unsigned int pk_bf(float a, float b) {
    return (unsigned int)f2bf(a) | ((unsigned int)f2bf(b) << 16);
}
__device__ __forceinline__ unsigned char f2fp8(float f) {
    return (unsigned char)(__builtin_amdgcn_cvt_pk_fp8_f32(f, f, 0, false) & 0xFF);
}
__device__ __forceinline__ short8 ld_frag(const unsigned short* p) {
    uint2 a = *(const uint2*)p;
    uint2 b = *(const uint2*)(p + 4);
    int4 v = make_int4((int)a.x, (int)a.y, (int)b.x, (int)b.y);
    return __builtin_bit_cast(short8, v);
}

// ---- weight pre-pack + buffer init (runs first) ---------------------------

__global__ void pack_kernel(const float* __restrict__ W0, const float* __restrict__ W1,
                            const float* __restrict__ W2, const float* __restrict__ W3,
                            unsigned short* __restrict__ P0, unsigned short* __restrict__ P1,
                            unsigned short* __restrict__ P2, unsigned short* __restrict__ P3,
                            int* __restrict__ gfill, unsigned char* __restrict__ t8zrowA,
                            unsigned char* __restrict__ t8zrowB, int NB) {
    if (blockIdx.x == 0) {                       // fold the memsets
        for (int i = threadIdx.x; i < NB; i += 256) gfill[i] = 0;
        if (threadIdx.x < 32) {
            ((unsigned int*)t8zrowA)[threadIdx.x] = 0;
            ((unsigned int*)t8zrowB)[threadIdx.x] = 0;
        }
    }
    int which = blockIdx.x >> 3;
    const float* W = which == 0 ? W0 : which == 1 ? W1 : which == 2 ? W2 : W3;
    unsigned short* P = which == 0 ? P0 : which == 1 ? P1 : which == 2 ? P2 : P3;
    int f = (blockIdx.x & 7) * 256 + threadIdx.x;
    int lane = f & 63, nt = (f >> 6) & 7, kc = f >> 9;
    int kbase = kc * 32 + (lane >> 4) * 8;
    int ncol = nt * 16 + (lane & 15);
    short8 frag;
    #pragma unroll
    for (int j = 0; j < 8; ++j)
        frag[j] = (short)f2bf(W[(size_t)(kbase + j) * 128 + ncol]);
    *((short8*)(P + (size_t)f * 8)) = frag;
}

// ---- graph build ----------------------------------------------------------
// entry = (d & 255) << 17 | src   (src < 2^17)

__global__ __launch_bounds__(512) void bin_kernel(
        const int* __restrict__ src, const int* __restrict__ dst,
        int* __restrict__ gfill, unsigned int* __restrict__ binbuf,
        int NB, int C, int E) {
    __shared__ int h4[4][NBMAX];     // per-group counts -> cursors
    __shared__ int start[NBMAX];
    __shared__ int tot[NBMAX];
    __shared__ int dstoff[NBMAX];
    int tid = threadIdx.x;
    int grp = tid >> 7;
    int e0 = blockIdx.x * BIN_CH;
    for (int i = tid; i < 4 * NBMAX; i += 512) ((int*)h4)[i] = 0;
    __syncthreads();
    for (int i = tid; i < BIN_CH; i += 512) {
        int e = e0 + i;
        if (e < E) atomicAdd(&h4[grp][dst[e] >> 8], 1);
    }
    __syncthreads();
    if (tid < 64) {        // wave 0: totals, exclusive scan, per-group bases
        int carry = 0;
        for (int base = 0; base < NB; base += 64) {
            int idx = base + tid;
            int c0 = 0, c1 = 0, c2 = 0, c3 = 0, v = 0;
            if (idx < NB) {
                c0 = h4[0][idx]; c1 = h4[1][idx];
                c2 = h4[2][idx]; c3 = h4[3][idx];
                v = c0 + c1 + c2 + c3;
            }
            int s = v;
            #pragma unroll
            for (int off = 1; off < 64; off <<= 1) {
                int u = __shfl_up(s, off);
                if (tid >= off) s += u;
            }
            if (idx < NB) {
                int ex = carry + s - v;
                start[idx] = ex;
                tot[idx] = v;
                h4[0][idx] = ex;
                h4[1][idx] = ex + c0;
                h4[2][idx] = ex + c0 + c1;
                h4[3][idx] = ex + c0 + c1 + c2;
            }
            carry += __shfl(s, 63);
        }
    }
    __syncthreads();
    for (int i = tid; i < NB; i += 512) {   // reserve global runs
        int cnt = tot[i];
        int g = cnt ? atomicAdd(&gfill[i], cnt) : 0;
        dstoff[i] = g - start[i];
    }
    __syncthreads();
    for (int i = tid; i < BIN_CH; i += 512) {
        int e = e0 + i;
        if (e >= E) continue;
        int d = dst[e];
        int b = d >> 8;
        int slot = atomicAdd(&h4[grp][b], 1);         // block-local rank
        int gidx = b * C + dstoff[b] + slot;
        if (gidx < (b + 1) * C)
            binbuf[gidx] = (unsigned int)src[e] | ((unsigned int)(d & 255) << 17);
    }
}

// one block per bucket: split hist(4x256) -> scan -> rowptr/dinv -> place.
// Bucket base computed in-kernel (wave 1 sums gfill[0..b)).
__global__ __launch_bounds__(256) void build_kernel(
        const unsigned int* __restrict__ binbuf, const int* __restrict__ gfill,
        int* __restrict__ rowptr, float* __restrict__ dinv, int* __restrict__ col,
        int NB, int C, int N, int E) {
    __shared__ int h4[4][BKT];       // per-group counts -> cursors
    __shared__ int hs[BKT];          // exclusive scan of totals
    __shared__ int tot[BKT];
    __shared__ int bbase_s;
    int b = blockIdx.x, tid = threadIdx.x;
    int grp = tid >> 6;
    int cnt = gfill[b];
    const unsigned int* p = binbuf + (size_t)b * C;
    for (int i = tid; i < 4 * BKT; i += 256) ((int*)h4)[i] = 0;
    __syncthreads();
    if (tid >= 64 && tid < 128) {          // wave 1: base = sum gfill[0..b)
        int l = tid - 64;
        int s = 0;
        for (int i = l; i < b; i += 64) s += gfill[i];
        #pragma unroll
        for (int off = 32; off > 0; off >>= 1) s += __shfl_down(s, off);
        if (l == 0) bbase_s = s;
    }
    for (int i = tid; i < cnt; i += 256) atomicAdd(&h4[grp][p[i] >> 17], 1);
    __syncthreads();
    if (tid < 64) {        // wave 0: totals, scan, per-group cursor bases
        int carry = 0;
        for (int base = 0; base < BKT; base += 64) {
            int idx = base + tid;
            int c0 = h4[0][idx], c1 = h4[1][idx], c2 = h4[2][idx], c3 = h4[3][idx];
            int v = c0 + c1 + c2 + c3;
            int s = v;
            #pragma unroll
            for (int off = 1; off < 64; off <<= 1) {
                int u = __shfl_up(s, off);
                if (tid >= off) s += u;
            }
            int ex = carry + s - v;
            hs[idx] = ex;
            tot[idx] = v;
            h4[0][idx] = ex;
            h4[1][idx] = ex + c0;
            h4[2][idx] = ex + c0 + c1;
            h4[3][idx] = ex + c0 + c1 + c2;
            carry += __shfl(s, 63);
        }
    }
    __syncthreads();
    int base = bbase_s;
    if (tid < BKT) {
        int node = b * BKT + tid;
        if (node < N) {
            rowptr[node] = base + hs[tid];
            dinv[node] = 1.0f / sqrtf((float)(tot[tid] + 1));
        }
    }
    if (b == 0 && tid == 0) rowptr[N] = E;
    __syncthreads();
    for (int i = tid; i < cnt; i += 256) {  // place via per-group cursors
        unsigned int u = p[i];
        int local = u >> 17;
        int pos = atomicAdd(&h4[grp][local], 1);
        col[base + pos] = (int)(u & 0x1FFFFu);
    }
}

// ---- input layer: t' = fp8( dinv_i * (x @ W_s) ) --------------------------

__global__ void in_gemm_kernel(const float* __restrict__ x, const float* __restrict__ W,
                               const float* __restrict__ dinv,
                               unsigned char* __restrict__ t8, int n) {
    int g = blockIdx.x * 256 + threadIdx.x;
    int i = g >> 6, c2 = g & 63;
    if (i >= n) return;
    float x0 = x[i * 3], x1 = x[i * 3 + 1], x2 = x[i * 3 + 2];
    float d = dinv[i];
    int c = c2 * 2;
    float v0 = d * (x0 * W[c]     + x1 * W[128 + c]     + x2 * W[256 + c]);
    float v1 = d * (x0 * W[c + 1] + x1 * W[128 + c + 1] + x2 * W[256 + c + 1]);
    unsigned int pk = __builtin_amdgcn_cvt_pk_fp8_f32(v0, v1, 0, false);
    ((unsigned short*)t8)[(size_t)i * 64 + c2] = (unsigned short)(pk & 0xFFFF);
}

// ---- split aggregation (pass 4): out_i = relu(d_i*(t'_i + sum t'_j) + b) --
// Baseline-proven: 16 nodes/block, 1 node per quarter-wave, bf16 out global.

__global__ __launch_bounds__(256) void agg_kernel(
        const unsigned char* __restrict__ t8, const int* __restrict__ rowptr,
        const int* __restrict__ col, const float* __restrict__ dinv,
        const float* __restrict__ bias, unsigned short* __restrict__ out, int n) {
    int node = blockIdx.x * 16 + (threadIdx.x >> 4);
    int lane = threadIdx.x & 63;
    int q16 = lane >> 4;            // quarter (node) within wave
    int lq  = lane & 15;            // edge slot within half-round
    int oct = (lane >> 3) & 1;      // which of 2 rows this lane helps load
    int l8  = lane & 7;             // 16B chunk within row
    if (node >= n) node = n - 1;    // dup work in tail, benign
    floatx2 acc[8];                 // cols 16*l8 .. +16
    #pragma unroll
    for (int i = 0; i < 8; ++i) acc[i] = (floatx2){0.f, 0.f};

    int beg = rowptr[node];
    int deg = rowptr[node + 1] - beg;
    for (int base = 0; base < deg; base += 32) {
        int m = deg - base;
        int jv0 = (lq < m)      ? col[beg + base + lq]      : n;   // n = zero row
        int jv1 = (lq + 16 < m) ? col[beg + base + 16 + lq] : n;
        uint4 v[16];
        #pragma unroll
        for (int q = 0; q < 8; ++q) {
            int j = __shfl(jv0, q16 * 16 + q * 2 + oct);
            v[q] = ((const uint4*)(t8 + (size_t)j * 128))[l8];
        }
        #pragma unroll
        for (int q = 0; q < 8; ++q) {
            int j = __shfl(jv1, q16 * 16 + q * 2 + oct);
            v[8 + q] = ((const uint4*)(t8 + (size_t)j * 128))[l8];
        }
        #pragma unroll
        for (int q = 0; q < 16; ++q) {
            acc[0] += __builtin_amdgcn_cvt_pk_f32_fp8(v[q].x, false);
            acc[1] += __builtin_amdgcn_cvt_pk_f32_fp8(v[q].x, true);
            acc[2] += __builtin_amdgcn_cvt_pk_f32_fp8(v[q].y, false);
            acc[3] += __builtin_amdgcn_cvt_pk_f32_fp8(v[q].y, true);
            acc[4] += __builtin_amdgcn_cvt_pk_f32_fp8(v[q].z, false);
            acc[5] += __builtin_amdgcn_cvt_pk_f32_fp8(v[q].z, true);
            acc[6] += __builtin_amdgcn_cvt_pk_f32_fp8(v[q].w, false);
            acc[7] += __builtin_amdgcn_cvt_pk_f32_fp8(v[q].w, true);
        }
    }
    #pragma unroll
    for (int i = 0; i < 8; ++i) {
        acc[i].x += __shfl_xor(acc[i].x, 8);
        acc[i].y += __shfl_xor(acc[i].y, 8);
    }
    uint4 s = ((const uint4*)(t8 + (size_t)node * 128))[l8];
    acc[0] += __builtin_amdgcn_cvt_pk_f32_fp8(s.x, false);
    acc[1] += __builtin_amdgcn_cvt_pk_f32_fp8(s.x, true);
    acc[2] += __builtin_amdgcn_cvt_pk_f32_fp8(s.y, false);
    acc[3] += __builtin_amdgcn_cvt_pk_f32_fp8(s.y, true);
    acc[4] += __builtin_amdgcn_cvt_pk_f32_fp8(s.z, false);
    acc[5] += __builtin_amdgcn_cvt_pk_f32_fp8(s.z, true);
    acc[6] += __builtin_amdgcn_cvt_pk_f32_fp8(s.w, false);
    acc[7] += __builtin_amdgcn_cvt_pk_f32_fp8(s.w, true);

    float di = dinv[node];
    const float4* b4 = (const float4*)bias;     // cols 16*l8 .. +16
    float o[16];
    #pragma unroll
    for (int k = 0; k < 4; ++k) {
        float4 bb = b4[l8 * 4 + k];
        o[k*4+0] = fmaxf(di * acc[k*2].x   + bb.x, 0.f);
        o[k*4+1] = fmaxf(di * acc[k*2].y   + bb.y, 0.f);
        o[k*4+2] = fmaxf(di * acc[k*2+1].x + bb.z, 0.f);
        o[k*4+3] = fmaxf(di * acc[k*2+1].y + bb.w, 0.f);
    }
    if (oct == 0) {
        uint4 w0, w1;
        w0.x = pk_bf(o[0],  o[1]);  w0.y = pk_bf(o[2],  o[3]);
        w0.z = pk_bf(o[4],  o[5]);  w0.w = pk_bf(o[6],  o[7]);
        w1.x = pk_bf(o[8],  o[9]);  w1.y = pk_bf(o[10], o[11]);
        w1.z = pk_bf(o[12], o[13]); w1.w = pk_bf(o[14], o[15]);
        ((uint4*)(out + (size_t)node * 128))[l8 * 2]     = w0;
        ((uint4*)(out + (size_t)node * 128))[l8 * 2 + 1] = w1;
    }
}

// ---- GEMM pieces: 16-row tiles (agg_gemm) ---------------------------------
// Ws points at global packed weights (L1/L2-hot, shared by all blocks).

__device__ __forceinline__ void gemm_regs16(const short8 af[4], const unsigned short* Ws,
                                            int lane, floatx4 acc[8]) {
    #pragma unroll
    for (int nt = 0; nt < 8; ++nt) acc[nt] = (floatx4){0.f, 0.f, 0.f, 0.f};
    #pragma unroll
    for (int kc = 0; kc < 4; ++kc) {
        #pragma unroll
        for (int nt = 0; nt < 8; ++nt) {
            short8 bf = *((const short8*)(Ws + ((kc * 8 + nt) * 64 + lane) * 8));
            acc[nt] = __builtin_amdgcn_mfma_f32_16x16x32_bf16(af[kc], bf, acc[nt], 0, 0, 0);
        }
    }
}

__device__ __forceinline__ void gemm_lds16(const unsigned short* Hs, const unsigned short* Ws,
                                           int wav, int lane, floatx4 acc[8]) {
    int quad = lane >> 4, mrow = lane & 15;
    short8 af[4];
    #pragma unroll
    for (int kc = 0; kc < 4; ++kc)
        af[kc] = ld_frag(Hs + (wav * 16 + mrow) * HS_STRIDE + (kc * 4 + quad) * 8);
    gemm_regs16(af, Ws, lane, acc);
}

// ---- GEMM pieces: 32-row wave tiles (decoder) -----------------------------

__device__ __forceinline__ void gemm_regs(const short8 af[2][4], const unsigned short* Ws,
                                          int lane, floatx4 acc[2][8]) {
    #pragma unroll
    for (int t = 0; t < 2; ++t)
        #pragma unroll
        for (int nt = 0; nt < 8; ++nt) acc[t][nt] = (floatx4){0.f, 0.f, 0.f, 0.f};
    #pragma unroll
    for (int kc = 0; kc < 4; ++kc) {
        #pragma unroll
        for (int nt = 0; nt < 8; ++nt) {
            short8 bf = *((const short8*)(Ws + ((kc * 8 + nt) * 64 + lane) * 8));
            acc[0][nt] = __builtin_amdgcn_mfma_f32_16x16x32_bf16(af[0][kc], bf, acc[0][nt], 0, 0, 0);
            acc[1][nt] = __builtin_amdgcn_mfma_f32_16x16x32_bf16(af[1][kc], bf, acc[1][nt], 0, 0, 0);
        }
    }
}

__device__ __forceinline__ void gemm_lds(const unsigned short* Hs, const unsigned short* Ws,
                                         int wav, int lane, floatx4 acc[2][8]) {
    int quad = lane >> 4, mrow = lane & 15;
    short8 af[2][4];
    #pragma unroll
    for (int t = 0; t < 2; ++t)
        #pragma unroll
        for (int kc = 0; kc < 4; ++kc)
            af[t][kc] = ld_frag(Hs + (wav * 32 + t * 16 + mrow) * HS_STRIDE + (kc * 4 + quad) * 8);
    gemm_regs(af, Ws, lane, acc);
}

__device__ __forceinline__ void relu_store_hs(
        unsigned short* Hs, const float* __restrict__ bias,
        floatx4 acc[2][8], int wav, int lane) {
    int quad = lane >> 4, mrow = lane & 15;
    #pragma unroll
    for (int t = 0; t < 2; ++t) {
        #pragma unroll
        for (int nt = 0; nt < 8; ++nt) {
            int colc = nt * 16 + mrow;
            float bcol = bias[colc];
            #pragma unroll
            for (int r = 0; r < 4; ++r) {
                int rowl = wav * 32 + t * 16 + quad * 4 + r;
                Hs[rowl * HS_STRIDE + colc] = f2bf(fmaxf(acc[t][nt][r] + bcol, 0.f));
            }
        }
    }
}

// ---- fused aggregation phase (R22): 64 nodes/block, 256 threads -----------
// Quarter-wave per node, 4 nodes sequential per quarter. No-spill body:
// on-demand col loads, no cross-iteration register state.

__device__ __forceinline__ void agg_to_hs64(
        const unsigned char* __restrict__ t8, const int* __restrict__ rowptr,
        const int* __restrict__ col, const float* __restrict__ dinv,
        const float* __restrict__ bias, unsigned short* Hs, int n) {
    int tid = threadIdx.x;
    int lane = tid & 63;
    int q16 = lane >> 4;            // quarter (node) within wave
    int lq  = lane & 15;            // edge slot within half-round
    int oct = (lane >> 3) & 1;      // which of 2 rows this lane helps load
    int l8  = lane & 7;             // 16B chunk within row
    int qrow0 = (tid >> 4) * 4;     // local row base for this quarter (0..60)
    const float4* b4 = (const float4*)bias;

    for (int it = 0; it < 4; ++it) {
        int rowl = qrow0 + it;
        int node = blockIdx.x * AG_ROWS + rowl;
        if (node >= n) node = n - 1;    // dup work in tail, benign
        floatx2 acc[8];                 // cols 16*l8 .. +16
        #pragma unroll
        for (int i = 0; i < 8; ++i) acc[i] = (floatx2){0.f, 0.f};

        int beg = rowptr[node];
        int deg = rowptr[node + 1] - beg;
        for (int base = 0; base < deg; base += 32) {
            int m = deg - base;
            int jv0 = (lq < m)      ? col[beg + base + lq]      : n;   // n = zero row
            int jv1 = (lq + 16 < m) ? col[beg + base + 16 + lq] : n;
            uint4 v[16];
            #pragma unroll
            for (int q = 0; q < 8; ++q) {
                int j = __shfl(jv0, q16 * 16 + q * 2 + oct);
                v[q] = ((const uint4*)(t8 + (size_t)j * 128))[l8];
            }
            #pragma unroll
            for (int q = 0; q < 8; ++q) {
                int j = __shfl(jv1, q16 * 16 + q * 2 + oct);
                v[8 + q] = ((const uint4*)(t8 + (size_t)j * 128))[l8];
            }
            #pragma unroll
            for (int q = 0; q < 16; ++q) {
                acc[0] += __builtin_amdgcn_cvt_pk_f32_fp8(v[q].x, false);
                acc[1] += __builtin_amdgcn_cvt_pk_f32_fp8(v[q].x, true);
                acc[2] += __builtin_amdgcn_cvt_pk_f32_fp8(v[q].y, false);
                acc[3] += __builtin_amdgcn_cvt_pk_f32_fp8(v[q].y, true);
                acc[4] += __builtin_amdgcn_cvt_pk_f32_fp8(v[q].z, false);
                acc[5] += __builtin_amdgcn_cvt_pk_f32_fp8(v[q].z, true);
                acc[6] += __builtin_amdgcn_cvt_pk_f32_fp8(v[q].w, false);
                acc[7] += __builtin_amdgcn_cvt_pk_f32_fp8(v[q].w, true);
            }
        }
        #pragma unroll
        for (int i = 0; i < 8; ++i) {
            acc[i].x += __shfl_xor(acc[i].x, 8);
            acc[i].y += __shfl_xor(acc[i].y, 8);
        }
        uint4 s = ((const uint4*)(t8 + (size_t)node * 128))[l8];
        acc[0] += __builtin_amdgcn_cvt_pk_f32_fp8(s.x, false);
        acc[1] += __builtin_amdgcn_cvt_pk_f32_fp8(s.x, true);
        acc[2] += __builtin_amdgcn_cvt_pk_f32_fp8(s.y, false);
        acc[3] += __builtin_amdgcn_cvt_pk_f32_fp8(s.y, true);
        acc[4] += __builtin_amdgcn_cvt_pk_f32_fp8(s.z, false);
        acc[5] += __builtin_amdgcn_cvt_pk_f32_fp8(s.z, true);
        acc[6] += __builtin_amdgcn_cvt_pk_f32_fp8(s.w, false);
        acc[7] += __builtin_amdgcn_cvt_pk_f32_fp8(s.w, true);

        float di = dinv[node];
        float o[16];
        #pragma unroll
        for (int k = 0; k < 4; ++k) {
            float4 bb = b4[l8 * 4 + k];
            o[k*4+0] = fmaxf(di * acc[k*2].x   + bb.x, 0.f);
            o[k*4+1] = fmaxf(di * acc[k*2].y   + bb.y, 0.f);
            o[k*4+2] = fmaxf(di * acc[k*2+1].x + bb.z, 0.f);
            o[k*4+3] = fmaxf(di * acc[k*2+1].y + bb.w, 0.f);
        }
        if (oct == 0) {                 // write bf16 row chunk to LDS
            unsigned short* hp = Hs + rowl * HS_STRIDE + l8 * 16;
            uint2 w;
            w.x = pk_bf(o[0],  o[1]);  w.y = pk_bf(o[2],  o[3]);
            *(uint2*)(hp)      = w;
            w.x = pk_bf(o[4],  o[5]);  w.y = pk_bf(o[6],  o[7]);
            *(uint2*)(hp + 4)  = w;
            w.x = pk_bf(o[8],  o[9]);  w.y = pk_bf(o[10], o[11]);
            *(uint2*)(hp + 8)  = w;
            w.x = pk_bf(o[12], o[13]); w.y = pk_bf(o[14], o[15]);
            *(uint2*)(hp + 12) = w;
        }
    }
}

// ---- fused agg + encoder GEMM: t8_out = fp8( dinv * (agg(t8_in) @ W) ) ----
// 64 rows/block, grid = ceil(N/64). One barrier agg->GEMM (row ownership
// crosses waves); all 4 waves then run independent 16-row GEMM tiles.

__global__ __launch_bounds__(256, 3) void agg_gemm_kernel(
        const unsigned char* __restrict__ t8, const int* __restrict__ rowptr,
        const int* __restrict__ col, const float* __restrict__ dinv,
        const float* __restrict__ bias, const unsigned short* __restrict__ Wp,
        unsigned char* __restrict__ outp, int n) {
    __shared__ unsigned short Hs[AG_ROWS * HS_STRIDE];
    agg_to_hs64(t8, rowptr, col, dinv, bias, Hs, n);
    __syncthreads();

    int tid = threadIdx.x;
    int wav = tid >> 6, lane = tid & 63;
    int quad = lane >> 4, mrow = lane & 15;
    int row0 = blockIdx.x * AG_ROWS + wav * 16;

    floatx4 acc[8];
    gemm_lds16(Hs, Wp, wav, lane, acc);

    int rbase = row0 + quad * 4;
    float dv[4];
    #pragma unroll
    for (int r = 0; r < 4; ++r)
        dv[r] = (rbase + r < n) ? dinv[rbase + r] : 0.f;
    #pragma unroll
    for (int nt = 0; nt < 8; ++nt) {
        int colc = nt * 16 + mrow;
        #pragma unroll
        for (int r = 0; r < 4; ++r) {
            int row = rbase + r;
            if (row < n)
                outp[(size_t)row * 128 + colc] = f2fp8(acc[nt][r] * dv[r]);
        }
    }
}

// ---- decoder (R18): GEMM(W_sd) -> GEMM(W_md) -> GEMM(W_md)+proj+residual --
// Wave-independent: weights from global, Hs rows wave-private, zero barriers.

__global__ __launch_bounds__(256, 4) void decoder_kernel(
        const unsigned short* __restrict__ A,
        const unsigned short* __restrict__ Wp_sd, const float* __restrict__ b_sd,
        const unsigned short* __restrict__ Wp_md, const float* __restrict__ b_md,
        const float* __restrict__ W_ed, const float* __restrict__ b_ed,
        const float* __restrict__ x, float* __restrict__ out, int n) {
    __shared__ unsigned short Hs[128 * HS_STRIDE];
    int tid = threadIdx.x;
    int wav = tid >> 6, lane = tid & 63;
    int quad = lane >> 4, mrow = lane & 15;
    int row0 = blockIdx.x * 128 + wav * 32;

    short8 af[2][4];
    #pragma unroll
    for (int t = 0; t < 2; ++t) {
        int arow = row0 + t * 16 + mrow; if (arow >= n) arow = n - 1;
        const unsigned short* abase = A + (size_t)arow * 128 + quad * 8;
        #pragma unroll
        for (int kc = 0; kc < 4; ++kc)
            af[t][kc] = *((const short8*)(abase + kc * 32));
    }

    floatx4 acc[2][8];
    // stage 1: h @ W_sd
    gemm_regs(af, Wp_sd, lane, acc);
    relu_store_hs(Hs, b_sd, acc, wav, lane);
    // stage 2: @ W_md (Hs rows are wave-private -> no barrier anywhere)
    gemm_lds(Hs, Wp_md, wav, lane, acc);
    relu_store_hs(Hs, b_md, acc, wav, lane);
    // stage 3: @ W_md
    gemm_lds(Hs, Wp_md, wav, lane, acc);

    // out-projection: relu(acc+b_md) @ W_ed + b_ed + x
    float wed[8][3];
    #pragma unroll
    for (int nt = 0; nt < 8; ++nt) {
        int c = nt * 16 + mrow;
        #pragma unroll
        for (int k = 0; k < 3; ++k) wed[nt][k] = W_ed[c * 3 + k];
    }
    #pragma unroll
    for (int t = 0; t < 2; ++t) {
        #pragma unroll
        for (int r = 0; r < 4; ++r) {
            float s0 = 0.f, s1 = 0.f, s2 = 0.f;
            #pragma unroll
            for (int nt = 0; nt < 8; ++nt) {
                float v = fmaxf(acc[t][nt][r] + b_md[nt * 16 + mrow], 0.f);
                s0 += v * wed[nt][0]; s1 += v * wed[nt][1]; s2 += v * wed[nt][2];
            }
            #pragma unroll
            for (int off = 1; off < 16; off <<= 1) {
                s0 += __shfl_xor(s0, off);
                s1 += __shfl_xor(s1, off);
                s2 += __shfl_xor(s2, off);
            }
            if (mrow == 0) {
                int row = row0 + t * 16 + quad * 4 + r;
                if (row < n) {
                    out[row * 3 + 0] = s0 + b_ed[0] + x[row * 3 + 0];
                    out[row * 3 + 1] = s1 + b_ed[1] + x[row * 3 + 1];
                    out[row * 3 + 2] = s2 + b_ed[2] + x[row * 3 + 2];
                }
            }
        }
    }
}

// ---------------------------------------------------------------------------

extern "C" void kernel_launch(void* const* d_in, const int* in_sizes, int n_in,
                              void* d_out, int out_size, void* d_ws, size_t ws_size,
                              hipStream_t stream) {
    const float* x    = (const float*)d_in[0];
    const int*   ei   = (const int*)d_in[1];
    const float* W_s  = (const float*)d_in[2];
    const float* b_s  = (const float*)d_in[3];
    const float* W_m  = (const float*)d_in[4];
    const float* b_m  = (const float*)d_in[5];
    const float* W_e  = (const float*)d_in[6];
    const float* b_e  = (const float*)d_in[7];
    const float* W_sd = (const float*)d_in[8];
    const float* b_sd = (const float*)d_in[9];
    const float* W_md = (const float*)d_in[10];
    const float* b_md = (const float*)d_in[11];
    const float* W_ed = (const float*)d_in[12];
    const float* b_ed = (const float*)d_in[13];
    float* outp = (float*)d_out;

    const int N = in_sizes[0] / 3;
    const int E = in_sizes[1] / 2;
    const int* src = ei;
    const int* dst = ei + E;

    const int NB = (N + BKT - 1) / BKT;                  // 256-node buckets
    const int C  = (((E / NB) * 3 / 2) + 255) & ~255;    // segment cap, 1.5x mean

    char* p = (char*)d_ws;
    auto carve = [&](size_t bytes) {
        void* r = (void*)p;
        p += (bytes + 255) & ~(size_t)255;
        return r;
    };
    int*   rowptr = (int*)  carve((size_t)(N + 1) * 4);
    int*   col    = (int*)  carve((size_t)E * 4);
    float* dinv   = (float*)carve((size_t)N * 4);
    int*   gfill  = (int*)  carve((size_t)NB * 4);
    unsigned int* binbuf = (unsigned int*)carve((size_t)NB * C * 4);
    unsigned short* Wp_m  = (unsigned short*)carve(16384 * 2);
    unsigned short* Wp_e  = (unsigned short*)carve(16384 * 2);
    unsigned short* Wp_sd = (unsigned short*)carve(16384 * 2);
    unsigned short* Wp_md = (unsigned short*)carve(16384 * 2);
    unsigned char*  T8a = (unsigned char*) carve((size_t)(N + 1) * 128);   // +1 zero row
    unsigned char*  T8b = (unsigned char*) carve((size_t)(N + 1) * 128);   // ping-pong
    unsigned short* A   = (unsigned short*)carve((size_t)N * 128 * 2);     // bf16 enc out
    (void)ws_size;

    const int gBin = (E + BIN_CH - 1) / BIN_CH;
    const int gRow64 = (N + AG_ROWS - 1) / AG_ROWS;
    const int gRow128 = (N + 127) / 128;
    const int gNode16 = (N + 15) / 16;

    // weight packs + buffer init (no deps)
    pack_kernel<<<32, 256, 0, stream>>>(W_m, W_e, W_sd, W_md, Wp_m, Wp_e, Wp_sd, Wp_md,
                                        gfill, T8a + (size_t)N * 128,
                                        T8b + (size_t)N * 128, NB);

    // graph build
    bin_kernel<<<gBin, 512, 0, stream>>>(src, dst, gfill, binbuf, NB, C, E);
    build_kernel<<<NB, 256, 0, stream>>>(binbuf, gfill, rowptr, dinv, col, NB, C, N, E);

    // encoder passes 1-3: fused agg+GEMM (ROWS=64), T8 ping-pong
    in_gemm_kernel<<<(N * 64 + 255) / 256, 256, 0, stream>>>(x, W_s, dinv, T8a, N);
    agg_gemm_kernel<<<gRow64, 256, 0, stream>>>(T8a, rowptr, col, dinv, b_s, Wp_m, T8b, N);
    agg_gemm_kernel<<<gRow64, 256, 0, stream>>>(T8b, rowptr, col, dinv, b_m, Wp_m, T8a, N);
    agg_gemm_kernel<<<gRow64, 256, 0, stream>>>(T8a, rowptr, col, dinv, b_m, Wp_e, T8b, N);

    // pass 4: split high-TLP agg -> global bf16 A, then barrier-free decoder
    agg_kernel<<<gNode16, 256, 0, stream>>>(T8b, rowptr, col, dinv, b_e, A, N);
    decoder_kernel<<<gRow128, 256, 0, stream>>>(A, Wp_sd, b_sd, Wp_md, b_md,
                                                W_ed, b_ed, x, outp, N);
}